// Round 11
// baseline (425.082 us; speedup 1.0000x reference)
//
#include <hip/hip_runtime.h>

#define N_NODES 100000
#define N_EDGES 1600000
#define IN_F    128
#define NEG_SLOPE 0.2f
#define NBUCK   512                 // scan width; active buckets = 391
#define PCHUNK  4096                // edges per partition block

typedef __attribute__((ext_vector_type(8))) short bf16x8;
typedef __attribute__((ext_vector_type(4))) float f32x4;

__device__ __forceinline__ float bf2f(unsigned short u) {
    return __uint_as_float(((unsigned int)u) << 16);
}

// f32 -> bf16 round-to-nearest-even
__device__ __forceinline__ unsigned short f2bf(float f) {
    unsigned int u = __float_as_uint(f);
    u += 0x7FFFu + ((u >> 16) & 1u);
    return (unsigned short)(u >> 16);
}

// ---------------------------------------------------------------------------
// Weight pack (all three matrices in one launch), bf16 fragment order:
// Wp[((nt*4+kt)*64+lane)*8+j] = W[kt*32+(lane>>4)*8+j][nt*16+(lane&15)]
// ---------------------------------------------------------------------------
__global__ __launch_bounds__(256) void pack_all(const float* __restrict__ W0,
                                                const float* __restrict__ W1,
                                                const float* __restrict__ W2,
                                                const float* __restrict__ rW2,
                                                unsigned short* __restrict__ W0p,
                                                unsigned short* __restrict__ W1p,
                                                unsigned short* __restrict__ W2p) {
    int gid = blockIdx.x * 256 + threadIdx.x;        // < 40960
    const float* W;
    unsigned short* Wp;
    int idx, ncols;
    if (gid < 16384)      { W = W0; Wp = W0p; idx = gid;          ncols = 128; }
    else if (gid < 32768) { W = W1; Wp = W1p; idx = gid - 16384;  ncols = 128; }
    else                  { W = W2; Wp = W2p; idx = gid - 32768;  ncols = 32;  }
    int j  = idx & 7;
    int l  = (idx >> 3) & 63;
    int kt = (idx >> 9) & 3;
    int nt = idx >> 11;
    int k  = kt * 32 + (l >> 4) * 8 + j;
    int n  = nt * 16 + (l & 15);
    float v;
    if (ncols == 128) v = W[k * 128 + n];
    else              v = (n < 16) ? W[k * 16 + n] : rW2[k * 16 + (n - 16)];
    Wp[idx] = f2bf(v);
}

// ---------------------------------------------------------------------------
// MFMA GEMM, f32 A (layer 0): featb(bf16) = A @ W, el/er fused. No LDS, no
// barrier: each lane loads its A-fragment directly (4 lanes/row fill a line).
// ---------------------------------------------------------------------------
__global__ __launch_bounds__(256) void gemm128_mfma_f32(const float* __restrict__ A,
                                                        const unsigned short* __restrict__ Wp,
                                                        const float* __restrict__ al,
                                                        const float* __restrict__ ar,
                                                        unsigned short* __restrict__ featb,
                                                        float* __restrict__ el,
                                                        float* __restrict__ er,
                                                        int nrows) {
    const int t    = threadIdx.x;
    const int wv   = t >> 6;
    const int lane = t & 63;
    const int q    = lane >> 4;
    const int m    = lane & 15;
    const int rb   = blockIdx.x * 64 + wv * 16;      // wave's row base
    const int arow = rb + m;
    const bool rok = arow < nrows;
    const float* Ar = A + (size_t)arow * IN_F;

    f32x4 acc[8];
#pragma unroll
    for (int nt = 0; nt < 8; ++nt) acc[nt] = (f32x4){0.f, 0.f, 0.f, 0.f};

#pragma unroll
    for (int kt = 0; kt < 4; ++kt) {
        bf16x8 afr = (bf16x8){0, 0, 0, 0, 0, 0, 0, 0};
        if (rok) {
            float4 v0 = *(const float4*)(Ar + kt * 32 + q * 8);
            float4 v1 = *(const float4*)(Ar + kt * 32 + q * 8 + 4);
            afr[0] = (short)f2bf(v0.x); afr[1] = (short)f2bf(v0.y);
            afr[2] = (short)f2bf(v0.z); afr[3] = (short)f2bf(v0.w);
            afr[4] = (short)f2bf(v1.x); afr[5] = (short)f2bf(v1.y);
            afr[6] = (short)f2bf(v1.z); afr[7] = (short)f2bf(v1.w);
        }
#pragma unroll
        for (int nt = 0; nt < 8; ++nt) {
            bf16x8 bfr = *(const bf16x8*)(Wp + ((size_t)(nt * 4 + kt) * 64 + lane) * 8);
            acc[nt] = __builtin_amdgcn_mfma_f32_16x16x32_bf16(afr, bfr, acc[nt], 0, 0, 0);
        }
    }

    float pel[16], per[16];
#pragma unroll
    for (int i = 0; i < 16; ++i) { pel[i] = 0.f; per[i] = 0.f; }

#pragma unroll
    for (int nt = 0; nt < 8; ++nt) {
        const int col = nt * 16 + m;
        const float alv = al[col];
        const float arv = ar[col];
        const int h = nt >> 1;
#pragma unroll
        for (int reg = 0; reg < 4; ++reg) {
            int row = rb + q * 4 + reg;
            float a = acc[nt][reg];
            if (row < nrows) featb[(size_t)row * 128 + col] = f2bf(a);
            pel[reg * 4 + h] += a * alv;
            per[reg * 4 + h] += a * arv;
        }
    }
#pragma unroll
    for (int s = 8; s > 0; s >>= 1) {
#pragma unroll
        for (int i = 0; i < 16; ++i) {
            pel[i] += __shfl_down(pel[i], s);
            per[i] += __shfl_down(per[i], s);
        }
    }
    if (m == 0) {
#pragma unroll
        for (int reg = 0; reg < 4; ++reg) {
            int row = rb + q * 4 + reg;
            if (row < nrows) {
#pragma unroll
                for (int h = 0; h < 4; ++h) {
                    el[row * 4 + h] = pel[reg * 4 + h];
                    er[row * 4 + h] = per[reg * 4 + h];
                }
            }
        }
    }
}

// ---------------------------------------------------------------------------
// MFMA GEMM, bf16 A (layer 1): same as above but A-frag is one 16B load.
// ---------------------------------------------------------------------------
__global__ __launch_bounds__(256) void gemm128_mfma_bf16(const unsigned short* __restrict__ Ab,
                                                         const unsigned short* __restrict__ Wp,
                                                         const float* __restrict__ al,
                                                         const float* __restrict__ ar,
                                                         unsigned short* __restrict__ featb,
                                                         float* __restrict__ el,
                                                         float* __restrict__ er,
                                                         int nrows) {
    const int t    = threadIdx.x;
    const int wv   = t >> 6;
    const int lane = t & 63;
    const int q    = lane >> 4;
    const int m    = lane & 15;
    const int rb   = blockIdx.x * 64 + wv * 16;
    const int arow = rb + m;
    const bool rok = arow < nrows;
    const unsigned short* Ar = Ab + (size_t)arow * IN_F;

    f32x4 acc[8];
#pragma unroll
    for (int nt = 0; nt < 8; ++nt) acc[nt] = (f32x4){0.f, 0.f, 0.f, 0.f};

#pragma unroll
    for (int kt = 0; kt < 4; ++kt) {
        bf16x8 afr = (bf16x8){0, 0, 0, 0, 0, 0, 0, 0};
        if (rok) afr = *(const bf16x8*)(Ar + kt * 32 + q * 8);
#pragma unroll
        for (int nt = 0; nt < 8; ++nt) {
            bf16x8 bfr = *(const bf16x8*)(Wp + ((size_t)(nt * 4 + kt) * 64 + lane) * 8);
            acc[nt] = __builtin_amdgcn_mfma_f32_16x16x32_bf16(afr, bfr, acc[nt], 0, 0, 0);
        }
    }

    float pel[16], per[16];
#pragma unroll
    for (int i = 0; i < 16; ++i) { pel[i] = 0.f; per[i] = 0.f; }

#pragma unroll
    for (int nt = 0; nt < 8; ++nt) {
        const int col = nt * 16 + m;
        const float alv = al[col];
        const float arv = ar[col];
        const int h = nt >> 1;
#pragma unroll
        for (int reg = 0; reg < 4; ++reg) {
            int row = rb + q * 4 + reg;
            float a = acc[nt][reg];
            if (row < nrows) featb[(size_t)row * 128 + col] = f2bf(a);
            pel[reg * 4 + h] += a * alv;
            per[reg * 4 + h] += a * arv;
        }
    }
#pragma unroll
    for (int s = 8; s > 0; s >>= 1) {
#pragma unroll
        for (int i = 0; i < 16; ++i) {
            pel[i] += __shfl_down(pel[i], s);
            per[i] += __shfl_down(per[i], s);
        }
    }
    if (m == 0) {
#pragma unroll
        for (int reg = 0; reg < 4; ++reg) {
            int row = rb + q * 4 + reg;
            if (row < nrows) {
#pragma unroll
                for (int h = 0; h < 4; ++h) {
                    el[row * 4 + h] = pel[reg * 4 + h];
                    er[row * 4 + h] = per[reg * 4 + h];
                }
            }
        }
    }
}

// ---------------------------------------------------------------------------
// MFMA dual GEMM layer 2 (bf16 A): [feat2b(bf16) | res2(f32)] = A @ [W2|resW2].
// ---------------------------------------------------------------------------
__global__ __launch_bounds__(256) void gemm16_mfma(const unsigned short* __restrict__ Ab,
                                                   const unsigned short* __restrict__ Wp,
                                                   const float* __restrict__ al,
                                                   const float* __restrict__ ar,
                                                   unsigned short* __restrict__ feat2b,
                                                   float* __restrict__ res2,
                                                   float* __restrict__ el,
                                                   float* __restrict__ er,
                                                   int nrows) {
    const int t    = threadIdx.x;
    const int wv   = t >> 6;
    const int lane = t & 63;
    const int q    = lane >> 4;
    const int m    = lane & 15;
    const int rb   = blockIdx.x * 64 + wv * 16;
    const int arow = rb + m;
    const bool rok = arow < nrows;
    const unsigned short* Ar = Ab + (size_t)arow * IN_F;

    f32x4 acc0 = (f32x4){0.f, 0.f, 0.f, 0.f};
    f32x4 acc1 = (f32x4){0.f, 0.f, 0.f, 0.f};

#pragma unroll
    for (int kt = 0; kt < 4; ++kt) {
        bf16x8 afr = (bf16x8){0, 0, 0, 0, 0, 0, 0, 0};
        if (rok) afr = *(const bf16x8*)(Ar + kt * 32 + q * 8);
        bf16x8 b0 = *(const bf16x8*)(Wp + ((size_t)(0 * 4 + kt) * 64 + lane) * 8);
        bf16x8 b1 = *(const bf16x8*)(Wp + ((size_t)(1 * 4 + kt) * 64 + lane) * 8);
        acc0 = __builtin_amdgcn_mfma_f32_16x16x32_bf16(afr, b0, acc0, 0, 0, 0);
        acc1 = __builtin_amdgcn_mfma_f32_16x16x32_bf16(afr, b1, acc1, 0, 0, 0);
    }

    float pel[4], per[4];
    const float alv = al[m];
    const float arv = ar[m];
#pragma unroll
    for (int reg = 0; reg < 4; ++reg) {
        int row = rb + q * 4 + reg;
        float a = acc0[reg];
        if (row < nrows) {
            feat2b[(size_t)row * 16 + m] = f2bf(a);
            res2[(size_t)row * 16 + m]   = acc1[reg];
        }
        pel[reg] = a * alv;
        per[reg] = a * arv;
    }
#pragma unroll
    for (int s = 8; s > 0; s >>= 1) {
#pragma unroll
        for (int reg = 0; reg < 4; ++reg) {
            pel[reg] += __shfl_down(pel[reg], s);
            per[reg] += __shfl_down(per[reg], s);
        }
    }
    if (m == 0) {
#pragma unroll
        for (int reg = 0; reg < 4; ++reg) {
            int row = rb + q * 4 + reg;
            if (row < nrows) { el[row] = pel[reg]; er[row] = per[reg]; }
        }
    }
}

// ---------------------------------------------------------------------------
// CSR build, locality-aware. Bucket = dst>>8. pe packed: (src<<8)|(dst&255).
// ---------------------------------------------------------------------------
__global__ __launch_bounds__(256) void bucket_count_k(const int* __restrict__ dst,
                                                      int* __restrict__ bcount, int nE) {
    __shared__ int hist[NBUCK];
    const int t = threadIdx.x;
    hist[t] = 0; hist[t + 256] = 0;
    __syncthreads();
    const int start = blockIdx.x * PCHUNK;
#pragma unroll
    for (int j = 0; j < PCHUNK / 256; ++j) {
        int e = start + j * 256 + t;
        if (e < nE) atomicAdd(&hist[dst[e] >> 8], 1);
    }
    __syncthreads();
    if (hist[t])       atomicAdd(&bcount[t],       hist[t]);
    if (hist[t + 256]) atomicAdd(&bcount[t + 256], hist[t + 256]);
}

__global__ __launch_bounds__(NBUCK) void scan512(const int* __restrict__ bcount,
                                                 int* __restrict__ bbase,
                                                 int* __restrict__ bcursor) {
    __shared__ int s[NBUCK];
    const int t = threadIdx.x;
    int v = bcount[t];
    s[t] = v;
    __syncthreads();
#pragma unroll
    for (int off = 1; off < NBUCK; off <<= 1) {
        int x = (t >= off) ? s[t - off] : 0;
        __syncthreads();
        s[t] += x;
        __syncthreads();
    }
    int excl = s[t] - v;
    bbase[t]   = excl;
    bcursor[t] = excl;
}

__global__ __launch_bounds__(512) void partition_k(const int* __restrict__ src,
                                                   const int* __restrict__ dst,
                                                   int* __restrict__ bcursor,
                                                   unsigned int* __restrict__ pe, int nE) {
    __shared__ int hist[NBUCK];
    __shared__ int lstart[NBUCK];
    __shared__ int gbase[NBUCK];
    __shared__ int curB[NBUCK];
    __shared__ unsigned int reorder[PCHUNK];

    const int t = threadIdx.x;
    const int start = blockIdx.x * PCHUNK;
    const int m = min(PCHUNK, nE - start);

    hist[t] = 0;
    __syncthreads();

#pragma unroll
    for (int j = 0; j < PCHUNK / 512; ++j) {
        int e = start + j * 512 + t;
        if (e < nE) atomicAdd(&hist[dst[e] >> 8], 1);
    }
    __syncthreads();
    const int cnt = hist[t];

    __shared__ int s[NBUCK];
    s[t] = cnt;
    __syncthreads();
#pragma unroll
    for (int off = 1; off < NBUCK; off <<= 1) {
        int x = (t >= off) ? s[t - off] : 0;
        __syncthreads();
        s[t] += x;
        __syncthreads();
    }
    lstart[t] = s[t] - cnt;
    curB[t]   = s[t] - cnt;
    gbase[t] = cnt ? atomicAdd(&bcursor[t], cnt) : 0;
    __syncthreads();

#pragma unroll
    for (int j = 0; j < PCHUNK / 512; ++j) {
        int e = start + j * 512 + t;
        if (e < nE) {
            int d = dst[e];
            int pos = atomicAdd(&curB[d >> 8], 1);
            reorder[pos] = ((unsigned)src[e] << 8) | ((unsigned)d & 255u);
        }
    }
    __syncthreads();

    for (int i = t; i < m; i += 512) {
        unsigned int ed = reorder[i];
        // position -> bucket via binary search over lstart (LDS, 9 steps)
        int lo = 0, hi = NBUCK - 1;
        while (lo < hi) {
            int mid = (lo + hi + 1) >> 1;
            if (lstart[mid] <= i) lo = mid; else hi = mid - 1;
        }
        pe[gbase[lo] + (i - lstart[lo])] = ed;
    }
}

__global__ __launch_bounds__(256) void bucket_finalize(const unsigned int* __restrict__ pe,
                                                       const int* __restrict__ bbase,
                                                       int* __restrict__ rowptr,
                                                       int* __restrict__ deg,
                                                       int* __restrict__ sorted_src,
                                                       int nE) {
    __shared__ int deg_l[256];
    __shared__ int s[256];
    __shared__ int cur[256];

    const int b  = blockIdx.x;
    const int t  = threadIdx.x;
    const int base = bbase[b];
    const int endE = (b + 1 < NBUCK) ? bbase[b + 1] : nE;
    const int cnt  = endE - base;
    const int n    = b * 256 + t;

    deg_l[t] = 0;
    __syncthreads();
    for (int i = t; i < cnt; i += 256)
        atomicAdd(&deg_l[pe[base + i] & 255u], 1);
    __syncthreads();

    const int dv = deg_l[t];
    s[t] = dv;
    __syncthreads();
#pragma unroll
    for (int off = 1; off < 256; off <<= 1) {
        int x = (t >= off) ? s[t - off] : 0;
        __syncthreads();
        s[t] += x;
        __syncthreads();
    }
    const int off_l = s[t] - dv;
    if (n < N_NODES) {
        rowptr[n] = base + off_l;
        deg[n]    = dv;
    }
    cur[t] = off_l;
    __syncthreads();

    for (int i = t; i < cnt; i += 256) {
        unsigned int ed = pe[base + i];
        int pos = atomicAdd(&cur[ed & 255u], 1);
        sorted_src[base + pos] = (int)(ed >> 8);
    }
}

// ---------------------------------------------------------------------------
// Pull aggregation, H=4, D=32, bf16 gathers, wave per node, bf16 in/out.
// Inner loop: src index is wave-uniform (LDS broadcast) -> readfirstlane
// scalarizes the gather base (SALU addressing, saddr-form loads); x2 unroll
// for two loads in flight. One full 256B row per load instruction.
// ---------------------------------------------------------------------------
__global__ __launch_bounds__(256) void gat_agg128(const int* __restrict__ rowptr,
                                                  const int* __restrict__ deg,
                                                  const int* __restrict__ sorted_src,
                                                  const float* __restrict__ el,
                                                  const float* __restrict__ er,
                                                  const unsigned short* __restrict__ featb,
                                                  const unsigned short* __restrict__ resb,
                                                  unsigned short* __restrict__ outb) {
    __shared__ int   sS[4][64];
    __shared__ float sW[4][64][4];

    const int wv   = threadIdx.x >> 6;
    const int lane = threadIdx.x & 63;
    const int nd   = blockIdx.x * 4 + wv;

    const int dg = deg[nd];
    const int r0 = rowptr[nd];
    const int h  = lane >> 4;
    const float4 er4 = *(const float4*)(er + nd * 4);

    float den = 0.f;
    float ax = 0.f, ay = 0.f;

    for (int base = 0; base < dg; base += 64) {
        int m = dg - base; if (m > 64) m = 64;
        if (lane < m) {
            int s = sorted_src[r0 + base + lane];
            sS[wv][lane] = s;
            float4 e4 = *(const float4*)(el + s * 4);
            float4 w;
            float v;
            v = e4.x + er4.x; v = v > 0.f ? v : NEG_SLOPE * v; w.x = __expf(v);
            v = e4.y + er4.y; v = v > 0.f ? v : NEG_SLOPE * v; w.y = __expf(v);
            v = e4.z + er4.z; v = v > 0.f ? v : NEG_SLOPE * v; w.z = __expf(v);
            v = e4.w + er4.w; v = v > 0.f ? v : NEG_SLOPE * v; w.w = __expf(v);
            *(float4*)(&sW[wv][lane][0]) = w;
        }
        // wave-synchronous: same wave wrote LDS
        int i = 0;
        for (; i + 1 < m; i += 2) {
            int s0 = __builtin_amdgcn_readfirstlane(sS[wv][i]);
            int s1 = __builtin_amdgcn_readfirstlane(sS[wv][i + 1]);
            float w0 = sW[wv][i][h];
            float w1 = sW[wv][i + 1][h];
            ushort2 u0 = *((const ushort2*)(featb + (size_t)s0 * 128) + lane);
            ushort2 u1 = *((const ushort2*)(featb + (size_t)s1 * 128) + lane);
            den += w0;
            ax += w0 * bf2f(u0.x);
            ay += w0 * bf2f(u0.y);
            den += w1;
            ax += w1 * bf2f(u1.x);
            ay += w1 * bf2f(u1.y);
        }
        if (i < m) {
            int s = __builtin_amdgcn_readfirstlane(sS[wv][i]);
            float w = sW[wv][i][h];
            ushort2 u = *((const ushort2*)(featb + (size_t)s * 128) + lane);
            den += w;
            ax += w * bf2f(u.x);
            ay += w * bf2f(u.y);
        }
    }

    float scale = den > 0.f ? 1.f / den : 0.f;
    float ox = ax * scale, oy = ay * scale;
    size_t o0 = (size_t)nd * 128 + lane * 2;
    if (resb) {
        ushort2 rv = *(const ushort2*)(resb + o0);
        ox += bf2f(rv.x);
        oy += bf2f(rv.y);
    }
    ox = fmaxf(ox, 0.f);
    oy = fmaxf(oy, 0.f);
    ushort2 ou;
    ou.x = f2bf(ox);
    ou.y = f2bf(oy);
    *(ushort2*)(outb + o0) = ou;
}

// ---------------------------------------------------------------------------
// Pull aggregation, H=1, C=16: wave per node, LDS staging, 8 edge-groups of
// 8 lanes; lane owns a feature pair. Final output f32 (+res2).
// ---------------------------------------------------------------------------
__global__ __launch_bounds__(256) void gat_agg16(const int* __restrict__ rowptr,
                                                 const int* __restrict__ deg,
                                                 const int* __restrict__ sorted_src,
                                                 const float* __restrict__ el,
                                                 const float* __restrict__ er,
                                                 const unsigned short* __restrict__ feat2b,
                                                 const float* __restrict__ res,
                                                 float* __restrict__ out) {
    __shared__ int   sS[4][64];
    __shared__ float sW[4][64];

    const int wv   = threadIdx.x >> 6;
    const int lane = threadIdx.x & 63;
    const int nd   = blockIdx.x * 4 + wv;
    const int g    = lane >> 3;
    const int f2   = (lane & 7) * 2;

    const int dg = deg[nd];
    const int r0 = rowptr[nd];
    const float erd = er[nd];

    float ax = 0.f, ay = 0.f, den = 0.f;

    for (int base = 0; base < dg; base += 64) {
        int m = dg - base; if (m > 64) m = 64;
        if (lane < m) {
            int s = sorted_src[r0 + base + lane];
            sS[wv][lane] = s;
            float v = el[s] + erd;
            v = v > 0.f ? v : NEG_SLOPE * v;
            sW[wv][lane] = __expf(v);
        }
        for (int i = g; i < m; i += 8) {
            int s   = sS[wv][i];
            float w = sW[wv][i];
            den += w;
            ushort2 u = *(const ushort2*)(feat2b + (size_t)s * 16 + f2);
            ax += w * bf2f(u.x);
            ay += w * bf2f(u.y);
        }
    }

    ax += __shfl_down(ax, 32); ay += __shfl_down(ay, 32); den += __shfl_down(den, 32);
    ax += __shfl_down(ax, 16); ay += __shfl_down(ay, 16); den += __shfl_down(den, 16);
    ax += __shfl_down(ax, 8);  ay += __shfl_down(ay, 8);  den += __shfl_down(den, 8);

    if (lane < 8) {
        float scale = den > 0.f ? 1.f / den : 0.f;
        size_t o0 = (size_t)nd * 16 + f2;
        float2 o;
        o.x = ax * scale + res[o0];
        o.y = ay * scale + res[o0 + 1];
        *(float2*)(out + o0) = o;
    }
}

// ---------------------------------------------------------------------------
extern "C" void kernel_launch(void* const* d_in, const int* in_sizes, int n_in,
                              void* d_out, int out_size, void* d_ws, size_t ws_size,
                              hipStream_t stream) {
    const float* inputs = (const float*)d_in[0];
    const int*   src    = (const int*)d_in[1];
    const int*   dst    = (const int*)d_in[2];
    const float* W0     = (const float*)d_in[3];
    const float* al0    = (const float*)d_in[4];
    const float* ar0    = (const float*)d_in[5];
    const float* W1     = (const float*)d_in[6];
    const float* al1    = (const float*)d_in[7];
    const float* ar1    = (const float*)d_in[8];
    const float* W2     = (const float*)d_in[9];
    const float* al2    = (const float*)d_in[10];
    const float* ar2    = (const float*)d_in[11];
    const float* resW2  = (const float*)d_in[12];
    float* out = (float*)d_out;

    const size_t NF = (size_t)N_NODES * 128;
    float* ws   = (float*)d_ws;
    float* el   = ws;                                  // N*4
    float* er   = el + (size_t)N_NODES * 4;            // N*4
    float* res2 = er + (size_t)N_NODES * 4;            // N*16
    unsigned short* hbufb  = (unsigned short*)(res2 + (size_t)N_NODES * 16);  // N*128 bf16
    unsigned short* featb  = hbufb + NF;               // N*128 bf16
    unsigned short* feat2b = featb + NF;               // N*16 bf16
    unsigned short* W0p    = feat2b + (size_t)N_NODES * 16;  // 16384
    unsigned short* W1p    = W0p + 16384;                    // 16384
    unsigned short* W2p    = W1p + 16384;                    // 8192
    int* iws = (int*)(W2p + 8192);
    unsigned int* pe = (unsigned int*)iws;             // E uint (packed)
    int* deg         = iws + N_EDGES;                  // N
    int* rowptr      = deg + N_NODES;                  // N
    int* sorted_src  = rowptr + N_NODES;               // E
    int* bcount      = sorted_src + N_EDGES;           // 512
    int* bbase       = bcount + NBUCK;                 // 512
    int* bcursor     = bbase + NBUCK;                  // 512

    dim3 blk(256);
    int gemmGrid = (N_NODES + 63) / 64;
    int pGrid    = (N_EDGES + PCHUNK - 1) / PCHUNK;    // 391
    int bGrid    = (N_NODES + 255) / 256;              // 391
    int aggGrid  = N_NODES / 4;                        // 25000

    // ---------------- CSR build + weight pack ------------------------------
    hipMemsetAsync(bcount, 0, NBUCK * sizeof(int), stream);
    bucket_count_k<<<pGrid, blk, 0, stream>>>(dst, bcount, N_EDGES);
    scan512<<<1, NBUCK, 0, stream>>>(bcount, bbase, bcursor);
    partition_k<<<pGrid, dim3(512), 0, stream>>>(src, dst, bcursor, pe, N_EDGES);
    bucket_finalize<<<bGrid, blk, 0, stream>>>(pe, bbase, rowptr, deg, sorted_src, N_EDGES);
    pack_all<<<160, blk, 0, stream>>>(W0, W1, W2, resW2, W0p, W1p, W2p);

    // ---------------- layer 0 ----------------
    gemm128_mfma_f32<<<gemmGrid, blk, 0, stream>>>(inputs, W0p, al0, ar0, featb,
                                                   el, er, N_NODES);
    gat_agg128<<<aggGrid, blk, 0, stream>>>(rowptr, deg, sorted_src, el, er, featb,
                                            nullptr, hbufb);

    // ---------------- layer 1 ----------------
    gemm128_mfma_bf16<<<gemmGrid, blk, 0, stream>>>(hbufb, W1p, al1, ar1, featb,
                                                    el, er, N_NODES);
    gat_agg128<<<aggGrid, blk, 0, stream>>>(rowptr, deg, sorted_src, el, er, featb,
                                            hbufb, hbufb);

    // ---------------- layer 2 ----------------
    gemm16_mfma<<<gemmGrid, blk, 0, stream>>>(hbufb, W2p, al2, ar2, feat2b, res2,
                                              el, er, N_NODES);
    gat_agg16<<<aggGrid, blk, 0, stream>>>(rowptr, deg, sorted_src, el, er, feat2b,
                                           res2, out);
}

// Round 12
// 423.585 us; speedup vs baseline: 1.0035x; 1.0035x over previous
//
#include <hip/hip_runtime.h>

#define N_NODES 100000
#define N_EDGES 1600000
#define IN_F    128
#define NEG_SLOPE 0.2f
#define NBUCK   512                 // scan width; active buckets = 391
#define PCHUNK  4096                // edges per partition block
#define PGRID   391                 // (N_EDGES + PCHUNK - 1) / PCHUNK
#define GEMMGRID 1563               // (N_NODES + 63) / 64
#define PACKGRID 160

typedef __attribute__((ext_vector_type(8))) short bf16x8;
typedef __attribute__((ext_vector_type(4))) float f32x4;
typedef __attribute__((ext_vector_type(2))) float f32x2;
typedef __attribute__((ext_vector_type(2))) unsigned short u16x2;

__device__ __forceinline__ float bf2f(unsigned short u) {
    return __uint_as_float(((unsigned int)u) << 16);
}

// f32 -> bf16 round-to-nearest-even
__device__ __forceinline__ unsigned short f2bf(float f) {
    unsigned int u = __float_as_uint(f);
    u += 0x7FFFu + ((u >> 16) & 1u);
    return (unsigned short)(u >> 16);
}

// ---------------------------------------------------------------------------
// Fused: bucket histogram (blocks [0,PGRID)) + weight pack (rest).
// Pack layout: Wp[((nt*4+kt)*64+lane)*8+j] = W[kt*32+(lane>>4)*8+j][nt*16+(lane&15)]
// ---------------------------------------------------------------------------
__global__ __launch_bounds__(256) void count_pack(const int* __restrict__ dst,
                                                  int* __restrict__ bcount, int nE,
                                                  const float* __restrict__ W0,
                                                  const float* __restrict__ W1,
                                                  const float* __restrict__ W2,
                                                  const float* __restrict__ rW2,
                                                  unsigned short* __restrict__ W0p,
                                                  unsigned short* __restrict__ W1p,
                                                  unsigned short* __restrict__ W2p) {
    __shared__ int hist[NBUCK];
    const int t = threadIdx.x;
    if (blockIdx.x < PGRID) {
        hist[t] = 0; hist[t + 256] = 0;
        __syncthreads();
        const int start = blockIdx.x * PCHUNK;
#pragma unroll
        for (int j = 0; j < PCHUNK / 256; ++j) {
            int e = start + j * 256 + t;
            if (e < nE) atomicAdd(&hist[__builtin_nontemporal_load(dst + e) >> 8], 1);
        }
        __syncthreads();
        if (hist[t])       atomicAdd(&bcount[t],       hist[t]);
        if (hist[t + 256]) atomicAdd(&bcount[t + 256], hist[t + 256]);
    } else {
        int gid = (blockIdx.x - PGRID) * 256 + t;        // < 40960
        const float* W;
        unsigned short* Wp;
        int idx, ncols;
        if (gid < 16384)      { W = W0; Wp = W0p; idx = gid;          ncols = 128; }
        else if (gid < 32768) { W = W1; Wp = W1p; idx = gid - 16384;  ncols = 128; }
        else                  { W = W2; Wp = W2p; idx = gid - 32768;  ncols = 32;  }
        int j  = idx & 7;
        int l  = (idx >> 3) & 63;
        int kt = (idx >> 9) & 3;
        int nt = idx >> 11;
        int k  = kt * 32 + (l >> 4) * 8 + j;
        int n  = nt * 16 + (l & 15);
        float v;
        if (ncols == 128) v = W[k * 128 + n];
        else              v = (n < 16) ? W[k * 16 + n] : rW2[k * 16 + (n - 16)];
        Wp[idx] = f2bf(v);
    }
}

__global__ __launch_bounds__(NBUCK) void scan512(const int* __restrict__ bcount,
                                                 int* __restrict__ bbase,
                                                 int* __restrict__ bcursor) {
    __shared__ int s[NBUCK];
    const int t = threadIdx.x;
    int v = bcount[t];
    s[t] = v;
    __syncthreads();
#pragma unroll
    for (int off = 1; off < NBUCK; off <<= 1) {
        int x = (t >= off) ? s[t - off] : 0;
        __syncthreads();
        s[t] += x;
        __syncthreads();
    }
    int excl = s[t] - v;
    bbase[t]   = excl;
    bcursor[t] = excl;
}

// ---------------------------------------------------------------------------
// Fused: edge partition (blocks [0,PGRID)) + layer-0 MFMA GEMM (rest).
// Partition: 256 thr, LDS counting sort, bucket id cached in bmem (no search).
// GEMM: featb(bf16) = inputs(f32) @ W0p, el/er fused; barrier-free.
// ---------------------------------------------------------------------------
__global__ __launch_bounds__(256) void part_gemm0(const int* __restrict__ src,
                                                  const int* __restrict__ dst,
                                                  int* __restrict__ bcursor,
                                                  unsigned int* __restrict__ pe, int nE,
                                                  const float* __restrict__ A,
                                                  const unsigned short* __restrict__ Wp,
                                                  const float* __restrict__ al,
                                                  const float* __restrict__ ar,
                                                  unsigned short* __restrict__ featb,
                                                  float* __restrict__ el,
                                                  float* __restrict__ er,
                                                  int nrows) {
    __shared__ int hist[NBUCK];
    __shared__ int lstart[NBUCK];
    __shared__ int gbase[NBUCK];
    __shared__ int curB[NBUCK];
    __shared__ int s[NBUCK];
    __shared__ unsigned int  reorder[PCHUNK];
    __shared__ unsigned short bmem[PCHUNK];

    const int t = threadIdx.x;

    if (blockIdx.x < PGRID) {
        const int start = blockIdx.x * PCHUNK;
        const int m = min(PCHUNK, nE - start);

        hist[t] = 0; hist[t + 256] = 0;
        __syncthreads();
#pragma unroll
        for (int j = 0; j < PCHUNK / 256; ++j) {
            int e = start + j * 256 + t;
            if (e < nE) atomicAdd(&hist[__builtin_nontemporal_load(dst + e) >> 8], 1);
        }
        __syncthreads();
        const int c0 = hist[t];
        const int c1 = hist[t + 256];
        s[t] = c0; s[t + 256] = c1;
        __syncthreads();
        // 512-wide inclusive scan with 256 threads
#pragma unroll
        for (int off = 1; off <= 256; off <<= 1) {
            int x0 = (t >= off) ? s[t - off] : 0;
            int x1 = s[t + 256 - off];
            __syncthreads();
            s[t] += x0; s[t + 256] += x1;
            __syncthreads();
        }
        lstart[t]       = s[t] - c0;
        lstart[t + 256] = s[t + 256] - c1;
        curB[t]         = s[t] - c0;
        curB[t + 256]   = s[t + 256] - c1;
        gbase[t]        = c0 ? atomicAdd(&bcursor[t],       c0) : 0;
        gbase[t + 256]  = c1 ? atomicAdd(&bcursor[t + 256], c1) : 0;
        __syncthreads();

#pragma unroll
        for (int j = 0; j < PCHUNK / 256; ++j) {
            int e = start + j * 256 + t;
            if (e < nE) {
                int d  = __builtin_nontemporal_load(dst + e);
                int sv = __builtin_nontemporal_load(src + e);
                int b  = d >> 8;
                int pos = atomicAdd(&curB[b], 1);
                reorder[pos] = ((unsigned)sv << 8) | ((unsigned)d & 255u);
                bmem[pos]    = (unsigned short)b;
            }
        }
        __syncthreads();

        for (int i = t; i < m; i += 256) {
            int b = bmem[i];
            __builtin_nontemporal_store(reorder[i], pe + gbase[b] + (i - lstart[b]));
        }
    } else {
        // ---------------- layer-0 GEMM ----------------
        const int bid  = blockIdx.x - PGRID;
        const int wv   = t >> 6;
        const int lane = t & 63;
        const int q    = lane >> 4;
        const int m    = lane & 15;
        const int rb   = bid * 64 + wv * 16;
        const int arow = rb + m;
        const bool rok = arow < nrows;
        const float* Ar = A + (size_t)arow * IN_F;

        f32x4 acc[8];
#pragma unroll
        for (int nt = 0; nt < 8; ++nt) acc[nt] = (f32x4){0.f, 0.f, 0.f, 0.f};

#pragma unroll
        for (int kt = 0; kt < 4; ++kt) {
            bf16x8 afr = (bf16x8){0, 0, 0, 0, 0, 0, 0, 0};
            if (rok) {
                f32x4 v0 = __builtin_nontemporal_load((const f32x4*)(Ar + kt * 32 + q * 8));
                f32x4 v1 = __builtin_nontemporal_load((const f32x4*)(Ar + kt * 32 + q * 8 + 4));
                afr[0] = (short)f2bf(v0.x); afr[1] = (short)f2bf(v0.y);
                afr[2] = (short)f2bf(v0.z); afr[3] = (short)f2bf(v0.w);
                afr[4] = (short)f2bf(v1.x); afr[5] = (short)f2bf(v1.y);
                afr[6] = (short)f2bf(v1.z); afr[7] = (short)f2bf(v1.w);
            }
#pragma unroll
            for (int nt = 0; nt < 8; ++nt) {
                bf16x8 bfr = *(const bf16x8*)(Wp + ((size_t)(nt * 4 + kt) * 64 + lane) * 8);
                acc[nt] = __builtin_amdgcn_mfma_f32_16x16x32_bf16(afr, bfr, acc[nt], 0, 0, 0);
            }
        }

        float pel[16], per[16];
#pragma unroll
        for (int i = 0; i < 16; ++i) { pel[i] = 0.f; per[i] = 0.f; }

#pragma unroll
        for (int nt = 0; nt < 8; ++nt) {
            const int col = nt * 16 + m;
            const float alv = al[col];
            const float arv = ar[col];
            const int h = nt >> 1;
#pragma unroll
            for (int reg = 0; reg < 4; ++reg) {
                int row = rb + q * 4 + reg;
                float a = acc[nt][reg];
                if (row < nrows) featb[(size_t)row * 128 + col] = f2bf(a);
                pel[reg * 4 + h] += a * alv;
                per[reg * 4 + h] += a * arv;
            }
        }
#pragma unroll
        for (int sh = 8; sh > 0; sh >>= 1) {
#pragma unroll
            for (int i = 0; i < 16; ++i) {
                pel[i] += __shfl_down(pel[i], sh);
                per[i] += __shfl_down(per[i], sh);
            }
        }
        if (m == 0) {
#pragma unroll
            for (int reg = 0; reg < 4; ++reg) {
                int row = rb + q * 4 + reg;
                if (row < nrows) {
#pragma unroll
                    for (int h = 0; h < 4; ++h) {
                        el[row * 4 + h] = pel[reg * 4 + h];
                        er[row * 4 + h] = per[reg * 4 + h];
                    }
                }
            }
        }
    }
}

__global__ __launch_bounds__(256) void bucket_finalize(const unsigned int* __restrict__ pe,
                                                       const int* __restrict__ bbase,
                                                       int* __restrict__ rowptr,
                                                       int* __restrict__ deg,
                                                       int* __restrict__ sorted_src,
                                                       int nE) {
    __shared__ int deg_l[256];
    __shared__ int s[256];
    __shared__ int cur[256];

    const int b  = blockIdx.x;
    const int t  = threadIdx.x;
    const int base = bbase[b];
    const int endE = (b + 1 < NBUCK) ? bbase[b + 1] : nE;
    const int cnt  = endE - base;
    const int n    = b * 256 + t;

    deg_l[t] = 0;
    __syncthreads();
    for (int i = t; i < cnt; i += 256)
        atomicAdd(&deg_l[__builtin_nontemporal_load(pe + base + i) & 255u], 1);
    __syncthreads();

    const int dv = deg_l[t];
    s[t] = dv;
    __syncthreads();
#pragma unroll
    for (int off = 1; off < 256; off <<= 1) {
        int x = (t >= off) ? s[t - off] : 0;
        __syncthreads();
        s[t] += x;
        __syncthreads();
    }
    const int off_l = s[t] - dv;
    if (n < N_NODES) {
        rowptr[n] = base + off_l;
        deg[n]    = dv;
    }
    cur[t] = off_l;
    __syncthreads();

    for (int i = t; i < cnt; i += 256) {
        unsigned int ed = __builtin_nontemporal_load(pe + base + i);
        int pos = atomicAdd(&cur[ed & 255u], 1);
        sorted_src[base + pos] = (int)(ed >> 8);
    }
}

// ---------------------------------------------------------------------------
// MFMA GEMM, bf16 A (layer 1): featb = Ab @ Wp, el/er fused. nt A-loads.
// ---------------------------------------------------------------------------
__global__ __launch_bounds__(256) void gemm128_mfma_bf16(const unsigned short* __restrict__ Ab,
                                                         const unsigned short* __restrict__ Wp,
                                                         const float* __restrict__ al,
                                                         const float* __restrict__ ar,
                                                         unsigned short* __restrict__ featb,
                                                         float* __restrict__ el,
                                                         float* __restrict__ er,
                                                         int nrows) {
    const int t    = threadIdx.x;
    const int wv   = t >> 6;
    const int lane = t & 63;
    const int q    = lane >> 4;
    const int m    = lane & 15;
    const int rb   = blockIdx.x * 64 + wv * 16;
    const int arow = rb + m;
    const bool rok = arow < nrows;
    const unsigned short* Ar = Ab + (size_t)arow * IN_F;

    f32x4 acc[8];
#pragma unroll
    for (int nt = 0; nt < 8; ++nt) acc[nt] = (f32x4){0.f, 0.f, 0.f, 0.f};

#pragma unroll
    for (int kt = 0; kt < 4; ++kt) {
        bf16x8 afr = (bf16x8){0, 0, 0, 0, 0, 0, 0, 0};
        if (rok) afr = __builtin_nontemporal_load((const bf16x8*)(Ar + kt * 32 + q * 8));
#pragma unroll
        for (int nt = 0; nt < 8; ++nt) {
            bf16x8 bfr = *(const bf16x8*)(Wp + ((size_t)(nt * 4 + kt) * 64 + lane) * 8);
            acc[nt] = __builtin_amdgcn_mfma_f32_16x16x32_bf16(afr, bfr, acc[nt], 0, 0, 0);
        }
    }

    float pel[16], per[16];
#pragma unroll
    for (int i = 0; i < 16; ++i) { pel[i] = 0.f; per[i] = 0.f; }

#pragma unroll
    for (int nt = 0; nt < 8; ++nt) {
        const int col = nt * 16 + m;
        const float alv = al[col];
        const float arv = ar[col];
        const int h = nt >> 1;
#pragma unroll
        for (int reg = 0; reg < 4; ++reg) {
            int row = rb + q * 4 + reg;
            float a = acc[nt][reg];
            if (row < nrows) featb[(size_t)row * 128 + col] = f2bf(a);
            pel[reg * 4 + h] += a * alv;
            per[reg * 4 + h] += a * arv;
        }
    }
#pragma unroll
    for (int sh = 8; sh > 0; sh >>= 1) {
#pragma unroll
        for (int i = 0; i < 16; ++i) {
            pel[i] += __shfl_down(pel[i], sh);
            per[i] += __shfl_down(per[i], sh);
        }
    }
    if (m == 0) {
#pragma unroll
        for (int reg = 0; reg < 4; ++reg) {
            int row = rb + q * 4 + reg;
            if (row < nrows) {
#pragma unroll
                for (int h = 0; h < 4; ++h) {
                    el[row * 4 + h] = pel[reg * 4 + h];
                    er[row * 4 + h] = per[reg * 4 + h];
                }
            }
        }
    }
}

// ---------------------------------------------------------------------------
// MFMA dual GEMM layer 2 (bf16 A): [feat2b(bf16) | res2(f32)] = A @ [W2|resW2].
// ---------------------------------------------------------------------------
__global__ __launch_bounds__(256) void gemm16_mfma(const unsigned short* __restrict__ Ab,
                                                   const unsigned short* __restrict__ Wp,
                                                   const float* __restrict__ al,
                                                   const float* __restrict__ ar,
                                                   unsigned short* __restrict__ feat2b,
                                                   float* __restrict__ res2,
                                                   float* __restrict__ el,
                                                   float* __restrict__ er,
                                                   int nrows) {
    const int t    = threadIdx.x;
    const int wv   = t >> 6;
    const int lane = t & 63;
    const int q    = lane >> 4;
    const int m    = lane & 15;
    const int rb   = blockIdx.x * 64 + wv * 16;
    const int arow = rb + m;
    const bool rok = arow < nrows;
    const unsigned short* Ar = Ab + (size_t)arow * IN_F;

    f32x4 acc0 = (f32x4){0.f, 0.f, 0.f, 0.f};
    f32x4 acc1 = (f32x4){0.f, 0.f, 0.f, 0.f};

#pragma unroll
    for (int kt = 0; kt < 4; ++kt) {
        bf16x8 afr = (bf16x8){0, 0, 0, 0, 0, 0, 0, 0};
        if (rok) afr = __builtin_nontemporal_load((const bf16x8*)(Ar + kt * 32 + q * 8));
        bf16x8 b0 = *(const bf16x8*)(Wp + ((size_t)(0 * 4 + kt) * 64 + lane) * 8);
        bf16x8 b1 = *(const bf16x8*)(Wp + ((size_t)(1 * 4 + kt) * 64 + lane) * 8);
        acc0 = __builtin_amdgcn_mfma_f32_16x16x32_bf16(afr, b0, acc0, 0, 0, 0);
        acc1 = __builtin_amdgcn_mfma_f32_16x16x32_bf16(afr, b1, acc1, 0, 0, 0);
    }

    float pel[4], per[4];
    const float alv = al[m];
    const float arv = ar[m];
#pragma unroll
    for (int reg = 0; reg < 4; ++reg) {
        int row = rb + q * 4 + reg;
        float a = acc0[reg];
        if (row < nrows) {
            feat2b[(size_t)row * 16 + m] = f2bf(a);
            __builtin_nontemporal_store(acc1[reg], res2 + (size_t)row * 16 + m);
        }
        pel[reg] = a * alv;
        per[reg] = a * arv;
    }
#pragma unroll
    for (int sh = 8; sh > 0; sh >>= 1) {
#pragma unroll
        for (int reg = 0; reg < 4; ++reg) {
            pel[reg] += __shfl_down(pel[reg], sh);
            per[reg] += __shfl_down(per[reg], sh);
        }
    }
    if (m == 0) {
#pragma unroll
        for (int reg = 0; reg < 4; ++reg) {
            int row = rb + q * 4 + reg;
            if (row < nrows) { el[row] = pel[reg]; er[row] = per[reg]; }
        }
    }
}

// ---------------------------------------------------------------------------
// Pull aggregation, H=4, D=32, bf16 gathers, wave per node, bf16 in/out.
// Round-10 loop structure (vector addressing — readfirstlane/half-wave both
// regressed; kernel is memory-latency bound). nt on streamed res/out.
// ---------------------------------------------------------------------------
__global__ __launch_bounds__(256) void gat_agg128(const int* __restrict__ rowptr,
                                                  const int* __restrict__ deg,
                                                  const int* __restrict__ sorted_src,
                                                  const float* __restrict__ el,
                                                  const float* __restrict__ er,
                                                  const unsigned short* __restrict__ featb,
                                                  const unsigned short* __restrict__ resb,
                                                  unsigned short* __restrict__ outb) {
    __shared__ int   sS[4][64];
    __shared__ float sW[4][64][4];

    const int wv   = threadIdx.x >> 6;
    const int lane = threadIdx.x & 63;
    const int nd   = blockIdx.x * 4 + wv;

    const int dg = deg[nd];
    const int r0 = rowptr[nd];
    const int h  = lane >> 4;
    const float4 er4 = *(const float4*)(er + nd * 4);

    float den = 0.f;
    float ax = 0.f, ay = 0.f;

    for (int base = 0; base < dg; base += 64) {
        int m = dg - base; if (m > 64) m = 64;
        if (lane < m) {
            int s = __builtin_nontemporal_load(sorted_src + r0 + base + lane);
            sS[wv][lane] = s;
            float4 e4 = *(const float4*)(el + s * 4);
            float4 w;
            float v;
            v = e4.x + er4.x; v = v > 0.f ? v : NEG_SLOPE * v; w.x = __expf(v);
            v = e4.y + er4.y; v = v > 0.f ? v : NEG_SLOPE * v; w.y = __expf(v);
            v = e4.z + er4.z; v = v > 0.f ? v : NEG_SLOPE * v; w.z = __expf(v);
            v = e4.w + er4.w; v = v > 0.f ? v : NEG_SLOPE * v; w.w = __expf(v);
            *(float4*)(&sW[wv][lane][0]) = w;
        }
        // wave-synchronous: same wave wrote LDS
        for (int i = 0; i < m; ++i) {
            int s   = sS[wv][i];
            float w = sW[wv][i][h];
            den += w;
            u16x2 u = *((const u16x2*)(featb + (size_t)s * 128) + lane);
            ax += w * bf2f(u.x);
            ay += w * bf2f(u.y);
        }
    }

    float scale = den > 0.f ? 1.f / den : 0.f;
    float ox = ax * scale, oy = ay * scale;
    size_t o0 = (size_t)nd * 128 + lane * 2;
    if (resb) {
        u16x2 rv = __builtin_nontemporal_load((const u16x2*)(resb + o0));
        ox += bf2f(rv.x);
        oy += bf2f(rv.y);
    }
    ox = fmaxf(ox, 0.f);
    oy = fmaxf(oy, 0.f);
    u16x2 ou;
    ou.x = f2bf(ox);
    ou.y = f2bf(oy);
    __builtin_nontemporal_store(ou, (u16x2*)(outb + o0));
}

// ---------------------------------------------------------------------------
// Pull aggregation, H=1, C=16: wave per node, LDS staging, 8 edge-groups of
// 8 lanes; lane owns a feature pair. Final output f32 (+res2), nt streamed.
// ---------------------------------------------------------------------------
__global__ __launch_bounds__(256) void gat_agg16(const int* __restrict__ rowptr,
                                                 const int* __restrict__ deg,
                                                 const int* __restrict__ sorted_src,
                                                 const float* __restrict__ el,
                                                 const float* __restrict__ er,
                                                 const unsigned short* __restrict__ feat2b,
                                                 const float* __restrict__ res,
                                                 float* __restrict__ out) {
    __shared__ int   sS[4][64];
    __shared__ float sW[4][64];

    const int wv   = threadIdx.x >> 6;
    const int lane = threadIdx.x & 63;
    const int nd   = blockIdx.x * 4 + wv;
    const int g    = lane >> 3;
    const int f2   = (lane & 7) * 2;

    const int dg = deg[nd];
    const int r0 = rowptr[nd];
    const float erd = er[nd];

    float ax = 0.f, ay = 0.f, den = 0.f;

    for (int base = 0; base < dg; base += 64) {
        int m = dg - base; if (m > 64) m = 64;
        if (lane < m) {
            int s = __builtin_nontemporal_load(sorted_src + r0 + base + lane);
            sS[wv][lane] = s;
            float v = el[s] + erd;
            v = v > 0.f ? v : NEG_SLOPE * v;
            sW[wv][lane] = __expf(v);
        }
        for (int i = g; i < m; i += 8) {
            int s   = sS[wv][i];
            float w = sW[wv][i];
            den += w;
            u16x2 u = *(const u16x2*)(feat2b + (size_t)s * 16 + f2);
            ax += w * bf2f(u.x);
            ay += w * bf2f(u.y);
        }
    }

    ax += __shfl_down(ax, 32); ay += __shfl_down(ay, 32); den += __shfl_down(den, 32);
    ax += __shfl_down(ax, 16); ay += __shfl_down(ay, 16); den += __shfl_down(den, 16);
    ax += __shfl_down(ax, 8);  ay += __shfl_down(ay, 8);  den += __shfl_down(den, 8);

    if (lane < 8) {
        float scale = den > 0.f ? 1.f / den : 0.f;
        size_t o0 = (size_t)nd * 16 + f2;
        f32x2 o;
        o.x = ax * scale + __builtin_nontemporal_load(res + o0);
        o.y = ay * scale + __builtin_nontemporal_load(res + o0 + 1);
        __builtin_nontemporal_store(o, (f32x2*)(out + o0));
    }
}

// ---------------------------------------------------------------------------
extern "C" void kernel_launch(void* const* d_in, const int* in_sizes, int n_in,
                              void* d_out, int out_size, void* d_ws, size_t ws_size,
                              hipStream_t stream) {
    const float* inputs = (const float*)d_in[0];
    const int*   src    = (const int*)d_in[1];
    const int*   dst    = (const int*)d_in[2];
    const float* W0     = (const float*)d_in[3];
    const float* al0    = (const float*)d_in[4];
    const float* ar0    = (const float*)d_in[5];
    const float* W1     = (const float*)d_in[6];
    const float* al1    = (const float*)d_in[7];
    const float* ar1    = (const float*)d_in[8];
    const float* W2     = (const float*)d_in[9];
    const float* al2    = (const float*)d_in[10];
    const float* ar2    = (const float*)d_in[11];
    const float* resW2  = (const float*)d_in[12];
    float* out = (float*)d_out;

    const size_t NF = (size_t)N_NODES * 128;
    float* ws   = (float*)d_ws;
    float* el   = ws;                                  // N*4
    float* er   = el + (size_t)N_NODES * 4;            // N*4
    float* res2 = er + (size_t)N_NODES * 4;            // N*16
    unsigned short* hbufb  = (unsigned short*)(res2 + (size_t)N_NODES * 16);  // N*128 bf16
    unsigned short* featb  = hbufb + NF;               // N*128 bf16
    unsigned short* feat2b = featb + NF;               // N*16 bf16
    unsigned short* W0p    = feat2b + (size_t)N_NODES * 16;  // 16384
    unsigned short* W1p    = W0p + 16384;                    // 16384
    unsigned short* W2p    = W1p + 16384;                    // 8192
    int* iws = (int*)(W2p + 8192);
    unsigned int* pe = (unsigned int*)iws;             // E uint (packed)
    int* deg         = iws + N_EDGES;                  // N
    int* rowptr      = deg + N_NODES;                  // N
    int* sorted_src  = rowptr + N_NODES;               // E
    int* bcount      = sorted_src + N_EDGES;           // 512
    int* bbase       = bcount + NBUCK;                 // 512
    int* bcursor     = bbase + NBUCK;                  // 512

    dim3 blk(256);
    int bGrid   = (N_NODES + 255) / 256;               // 391
    int aggGrid = N_NODES / 4;                         // 25000

    // ---------------- CSR build + pack + layer-0 GEMM (fused/overlapped) ---
    hipMemsetAsync(bcount, 0, NBUCK * sizeof(int), stream);
    count_pack<<<PGRID + PACKGRID, blk, 0, stream>>>(dst, bcount, N_EDGES,
                                                     W0, W1, W2, resW2, W0p, W1p, W2p);
    scan512<<<1, NBUCK, 0, stream>>>(bcount, bbase, bcursor);
    part_gemm0<<<PGRID + GEMMGRID, blk, 0, stream>>>(src, dst, bcursor, pe, N_EDGES,
                                                     inputs, W0p, al0, ar0, featb,
                                                     el, er, N_NODES);
    bucket_finalize<<<bGrid, blk, 0, stream>>>(pe, bbase, rowptr, deg, sorted_src, N_EDGES);

    // ---------------- layer 0 aggregation ----------------
    gat_agg128<<<aggGrid, blk, 0, stream>>>(rowptr, deg, sorted_src, el, er, featb,
                                            nullptr, hbufb);

    // ---------------- layer 1 ----------------
    gemm128_mfma_bf16<<<GEMMGRID, blk, 0, stream>>>(hbufb, W1p, al1, ar1, featb,
                                                    el, er, N_NODES);
    gat_agg128<<<aggGrid, blk, 0, stream>>>(rowptr, deg, sorted_src, el, er, featb,
                                            hbufb, hbufb);

    // ---------------- layer 2 ----------------
    gemm16_mfma<<<GEMMGRID, blk, 0, stream>>>(hbufb, W2p, al2, ar2, feat2b, res2,
                                              el, er, N_NODES);
    gat_agg16<<<aggGrid, blk, 0, stream>>>(rowptr, deg, sorted_src, el, er, feat2b,
                                           res2, out);
}

// Round 13
// 387.081 us; speedup vs baseline: 1.0982x; 1.0943x over previous
//
#include <hip/hip_runtime.h>

#define N_NODES 100000
#define N_EDGES 1600000
#define IN_F    128
#define NEG_SLOPE 0.2f
#define NBUCK   512                 // bucket = dst>>8; 391 active
#define BCAP    5120                // padded bucket capacity (mean 4096, +16 sigma)
#define PCHUNK  4096                // edges per partition block
#define PGRID   391                 // ceil(N_EDGES / PCHUNK)
#define GEMMGRID 1563               // ceil(N_NODES / 64)

typedef __attribute__((ext_vector_type(8))) short bf16x8;
typedef __attribute__((ext_vector_type(4))) float f32x4;

__device__ __forceinline__ float bf2f(unsigned short u) {
    return __uint_as_float(((unsigned int)u) << 16);
}

// f32 -> bf16 round-to-nearest-even
__device__ __forceinline__ unsigned short f2bf(float f) {
    unsigned int u = __float_as_uint(f);
    u += 0x7FFFu + ((u >> 16) & 1u);
    return (unsigned short)(u >> 16);
}

// ---------------------------------------------------------------------------
// K1: cursor init (blocks 0..1) + weight pack (blocks 2..161).
// Pack layout: Wp[((nt*4+kt)*64+lane)*8+j] = W[kt*32+(lane>>4)*8+j][nt*16+(lane&15)]
// ---------------------------------------------------------------------------
__global__ __launch_bounds__(256) void init_pack(int* __restrict__ bcursor,
                                                 const float* __restrict__ W0,
                                                 const float* __restrict__ W1,
                                                 const float* __restrict__ W2,
                                                 const float* __restrict__ rW2,
                                                 unsigned short* __restrict__ W0p,
                                                 unsigned short* __restrict__ W1p,
                                                 unsigned short* __restrict__ W2p) {
    const int t = threadIdx.x;
    if (blockIdx.x < 2) {
        int i = blockIdx.x * 256 + t;
        if (i < NBUCK) bcursor[i] = i * BCAP;
        return;
    }
    int gid = (blockIdx.x - 2) * 256 + t;            // < 40960
    const float* W;
    unsigned short* Wp;
    int idx, ncols;
    if (gid < 16384)      { W = W0; Wp = W0p; idx = gid;          ncols = 128; }
    else if (gid < 32768) { W = W1; Wp = W1p; idx = gid - 16384;  ncols = 128; }
    else                  { W = W2; Wp = W2p; idx = gid - 32768;  ncols = 32;  }
    int j  = idx & 7;
    int l  = (idx >> 3) & 63;
    int kt = (idx >> 9) & 3;
    int nt = idx >> 11;
    int k  = kt * 32 + (l >> 4) * 8 + j;
    int n  = nt * 16 + (l & 15);
    float v;
    if (ncols == 128) v = W[k * 128 + n];
    else              v = (n < 16) ? W[k * 16 + n] : rW2[k * 16 + (n - 16)];
    Wp[idx] = f2bf(v);
}

// ---------------------------------------------------------------------------
// K2: edge partition into padded buckets (blocks [0,PGRID)) + layer-0 MFMA
// GEMM (blocks [PGRID, PGRID+GEMMGRID)). Partition: LDS counting sort per
// 4096-edge chunk, per-bucket contiguous run flush (1 thread per bucket).
// GEMM: featb(bf16) = inputs(f32) @ W0p, el/er fused; barrier-free.
// ---------------------------------------------------------------------------
__global__ __launch_bounds__(256) void part_gemm0(const int* __restrict__ src,
                                                  const int* __restrict__ dst,
                                                  int* __restrict__ bcursor,
                                                  unsigned int* __restrict__ pe, int nE,
                                                  const float* __restrict__ A,
                                                  const unsigned short* __restrict__ Wp,
                                                  const float* __restrict__ al,
                                                  const float* __restrict__ ar,
                                                  unsigned short* __restrict__ featb,
                                                  float* __restrict__ el,
                                                  float* __restrict__ er,
                                                  int nrows) {
    __shared__ int hist[NBUCK];
    __shared__ int lstart[NBUCK];
    __shared__ int gbase[NBUCK];
    __shared__ int curB[NBUCK];
    __shared__ int s[NBUCK];
    __shared__ unsigned int reorder[PCHUNK];

    const int t = threadIdx.x;

    if (blockIdx.x < PGRID) {
        const int start = blockIdx.x * PCHUNK;

        hist[t] = 0; hist[t + 256] = 0;
        __syncthreads();
#pragma unroll
        for (int j = 0; j < PCHUNK / 256; ++j) {
            int e = start + j * 256 + t;
            if (e < nE) atomicAdd(&hist[dst[e] >> 8], 1);
        }
        __syncthreads();
        const int c0 = hist[t];
        const int c1 = hist[t + 256];
        s[t] = c0; s[t + 256] = c1;
        __syncthreads();
        // 512-wide inclusive scan with 256 threads
#pragma unroll
        for (int off = 1; off <= 256; off <<= 1) {
            int x0 = (t >= off) ? s[t - off] : 0;
            int x1 = s[t + 256 - off];
            __syncthreads();
            s[t] += x0; s[t + 256] += x1;
            __syncthreads();
        }
        lstart[t]       = s[t] - c0;
        lstart[t + 256] = s[t + 256] - c1;
        curB[t]         = s[t] - c0;
        curB[t + 256]   = s[t + 256] - c1;
        gbase[t]        = c0 ? atomicAdd(&bcursor[t],       c0) : 0;
        gbase[t + 256]  = c1 ? atomicAdd(&bcursor[t + 256], c1) : 0;
        __syncthreads();

#pragma unroll
        for (int j = 0; j < PCHUNK / 256; ++j) {
            int e = start + j * 256 + t;
            if (e < nE) {
                int d  = dst[e];
                int sv = src[e];
                int b  = d >> 8;
                int pos = atomicAdd(&curB[b], 1);
                reorder[pos] = ((unsigned)sv << 8) | ((unsigned)d & 255u);
            }
        }
        __syncthreads();

        // flush: one thread per bucket writes its contiguous run
        for (int b = t; b < NBUCK; b += 256) {
            int st = lstart[b];
            int en = curB[b];
            int gb = gbase[b];
            for (int k = st; k < en; ++k)
                pe[gb + (k - st)] = reorder[k];
        }
    } else {
        // ---------------- layer-0 GEMM ----------------
        const int bid  = blockIdx.x - PGRID;
        const int wv   = t >> 6;
        const int lane = t & 63;
        const int q    = lane >> 4;
        const int m    = lane & 15;
        const int rb   = bid * 64 + wv * 16;
        const int arow = rb + m;
        const bool rok = arow < nrows;
        const float* Ar = A + (size_t)arow * IN_F;

        f32x4 acc[8];
#pragma unroll
        for (int nt = 0; nt < 8; ++nt) acc[nt] = (f32x4){0.f, 0.f, 0.f, 0.f};

#pragma unroll
        for (int kt = 0; kt < 4; ++kt) {
            bf16x8 afr = (bf16x8){0, 0, 0, 0, 0, 0, 0, 0};
            if (rok) {
                float4 v0 = *(const float4*)(Ar + kt * 32 + q * 8);
                float4 v1 = *(const float4*)(Ar + kt * 32 + q * 8 + 4);
                afr[0] = (short)f2bf(v0.x); afr[1] = (short)f2bf(v0.y);
                afr[2] = (short)f2bf(v0.z); afr[3] = (short)f2bf(v0.w);
                afr[4] = (short)f2bf(v1.x); afr[5] = (short)f2bf(v1.y);
                afr[6] = (short)f2bf(v1.z); afr[7] = (short)f2bf(v1.w);
            }
#pragma unroll
            for (int nt = 0; nt < 8; ++nt) {
                bf16x8 bfr = *(const bf16x8*)(Wp + ((size_t)(nt * 4 + kt) * 64 + lane) * 8);
                acc[nt] = __builtin_amdgcn_mfma_f32_16x16x32_bf16(afr, bfr, acc[nt], 0, 0, 0);
            }
        }

        float pel[16], per[16];
#pragma unroll
        for (int i = 0; i < 16; ++i) { pel[i] = 0.f; per[i] = 0.f; }

#pragma unroll
        for (int nt = 0; nt < 8; ++nt) {
            const int col = nt * 16 + m;
            const float alv = al[col];
            const float arv = ar[col];
            const int h = nt >> 1;
#pragma unroll
            for (int reg = 0; reg < 4; ++reg) {
                int row = rb + q * 4 + reg;
                float a = acc[nt][reg];
                if (row < nrows) featb[(size_t)row * 128 + col] = f2bf(a);
                pel[reg * 4 + h] += a * alv;
                per[reg * 4 + h] += a * arv;
            }
        }
#pragma unroll
        for (int sh = 8; sh > 0; sh >>= 1) {
#pragma unroll
            for (int i = 0; i < 16; ++i) {
                pel[i] += __shfl_down(pel[i], sh);
                per[i] += __shfl_down(per[i], sh);
            }
        }
        if (m == 0) {
#pragma unroll
            for (int reg = 0; reg < 4; ++reg) {
                int row = rb + q * 4 + reg;
                if (row < nrows) {
#pragma unroll
                    for (int h = 0; h < 4; ++h) {
                        el[row * 4 + h] = pel[reg * 4 + h];
                        er[row * 4 + h] = per[reg * 4 + h];
                    }
                }
            }
        }
    }
}

// ---------------------------------------------------------------------------
// K3: per-bucket finalize — degree histogram + local scan -> rowptr/deg,
// within-bucket sort -> sorted_src (padded space, base = b*BCAP).
// ---------------------------------------------------------------------------
__global__ __launch_bounds__(256) void bucket_finalize(const unsigned int* __restrict__ pe,
                                                       const int* __restrict__ bcursor,
                                                       int* __restrict__ rowptr,
                                                       int* __restrict__ deg,
                                                       int* __restrict__ sorted_src) {
    __shared__ int deg_l[256];
    __shared__ int s[256];
    __shared__ int cur[256];

    const int b  = blockIdx.x;
    const int t  = threadIdx.x;
    const int base = b * BCAP;
    const int cnt  = bcursor[b] - base;
    const int n    = b * 256 + t;

    deg_l[t] = 0;
    __syncthreads();
    for (int i = t; i < cnt; i += 256)
        atomicAdd(&deg_l[pe[base + i] & 255u], 1);
    __syncthreads();

    const int dv = deg_l[t];
    s[t] = dv;
    __syncthreads();
#pragma unroll
    for (int off = 1; off < 256; off <<= 1) {
        int x = (t >= off) ? s[t - off] : 0;
        __syncthreads();
        s[t] += x;
        __syncthreads();
    }
    const int off_l = s[t] - dv;
    if (n < N_NODES) {
        rowptr[n] = base + off_l;
        deg[n]    = dv;
    }
    cur[t] = off_l;
    __syncthreads();

    for (int i = t; i < cnt; i += 256) {
        unsigned int ed = pe[base + i];
        int pos = atomicAdd(&cur[ed & 255u], 1);
        sorted_src[base + pos] = (int)(ed >> 8);
    }
}

// ---------------------------------------------------------------------------
// MFMA GEMM, bf16 A (layer 1): featb = Ab @ Wp, el/er fused. Barrier-free.
// ---------------------------------------------------------------------------
__global__ __launch_bounds__(256) void gemm128_mfma_bf16(const unsigned short* __restrict__ Ab,
                                                         const unsigned short* __restrict__ Wp,
                                                         const float* __restrict__ al,
                                                         const float* __restrict__ ar,
                                                         unsigned short* __restrict__ featb,
                                                         float* __restrict__ el,
                                                         float* __restrict__ er,
                                                         int nrows) {
    const int t    = threadIdx.x;
    const int wv   = t >> 6;
    const int lane = t & 63;
    const int q    = lane >> 4;
    const int m    = lane & 15;
    const int rb   = blockIdx.x * 64 + wv * 16;
    const int arow = rb + m;
    const bool rok = arow < nrows;
    const unsigned short* Ar = Ab + (size_t)arow * IN_F;

    f32x4 acc[8];
#pragma unroll
    for (int nt = 0; nt < 8; ++nt) acc[nt] = (f32x4){0.f, 0.f, 0.f, 0.f};

#pragma unroll
    for (int kt = 0; kt < 4; ++kt) {
        bf16x8 afr = (bf16x8){0, 0, 0, 0, 0, 0, 0, 0};
        if (rok) afr = *(const bf16x8*)(Ar + kt * 32 + q * 8);
#pragma unroll
        for (int nt = 0; nt < 8; ++nt) {
            bf16x8 bfr = *(const bf16x8*)(Wp + ((size_t)(nt * 4 + kt) * 64 + lane) * 8);
            acc[nt] = __builtin_amdgcn_mfma_f32_16x16x32_bf16(afr, bfr, acc[nt], 0, 0, 0);
        }
    }

    float pel[16], per[16];
#pragma unroll
    for (int i = 0; i < 16; ++i) { pel[i] = 0.f; per[i] = 0.f; }

#pragma unroll
    for (int nt = 0; nt < 8; ++nt) {
        const int col = nt * 16 + m;
        const float alv = al[col];
        const float arv = ar[col];
        const int h = nt >> 1;
#pragma unroll
        for (int reg = 0; reg < 4; ++reg) {
            int row = rb + q * 4 + reg;
            float a = acc[nt][reg];
            if (row < nrows) featb[(size_t)row * 128 + col] = f2bf(a);
            pel[reg * 4 + h] += a * alv;
            per[reg * 4 + h] += a * arv;
        }
    }
#pragma unroll
    for (int sh = 8; sh > 0; sh >>= 1) {
#pragma unroll
        for (int i = 0; i < 16; ++i) {
            pel[i] += __shfl_down(pel[i], sh);
            per[i] += __shfl_down(per[i], sh);
        }
    }
    if (m == 0) {
#pragma unroll
        for (int reg = 0; reg < 4; ++reg) {
            int row = rb + q * 4 + reg;
            if (row < nrows) {
#pragma unroll
                for (int h = 0; h < 4; ++h) {
                    el[row * 4 + h] = pel[reg * 4 + h];
                    er[row * 4 + h] = per[reg * 4 + h];
                }
            }
        }
    }
}

// ---------------------------------------------------------------------------
// MFMA dual GEMM layer 2 (bf16 A): [feat2b(bf16) | res2(f32)] = A @ [W2|resW2].
// ---------------------------------------------------------------------------
__global__ __launch_bounds__(256) void gemm16_mfma(const unsigned short* __restrict__ Ab,
                                                   const unsigned short* __restrict__ Wp,
                                                   const float* __restrict__ al,
                                                   const float* __restrict__ ar,
                                                   unsigned short* __restrict__ feat2b,
                                                   float* __restrict__ res2,
                                                   float* __restrict__ el,
                                                   float* __restrict__ er,
                                                   int nrows) {
    const int t    = threadIdx.x;
    const int wv   = t >> 6;
    const int lane = t & 63;
    const int q    = lane >> 4;
    const int m    = lane & 15;
    const int rb   = blockIdx.x * 64 + wv * 16;
    const int arow = rb + m;
    const bool rok = arow < nrows;
    const unsigned short* Ar = Ab + (size_t)arow * IN_F;

    f32x4 acc0 = (f32x4){0.f, 0.f, 0.f, 0.f};
    f32x4 acc1 = (f32x4){0.f, 0.f, 0.f, 0.f};

#pragma unroll
    for (int kt = 0; kt < 4; ++kt) {
        bf16x8 afr = (bf16x8){0, 0, 0, 0, 0, 0, 0, 0};
        if (rok) afr = *(const bf16x8*)(Ar + kt * 32 + q * 8);
        bf16x8 b0 = *(const bf16x8*)(Wp + ((size_t)(0 * 4 + kt) * 64 + lane) * 8);
        bf16x8 b1 = *(const bf16x8*)(Wp + ((size_t)(1 * 4 + kt) * 64 + lane) * 8);
        acc0 = __builtin_amdgcn_mfma_f32_16x16x32_bf16(afr, b0, acc0, 0, 0, 0);
        acc1 = __builtin_amdgcn_mfma_f32_16x16x32_bf16(afr, b1, acc1, 0, 0, 0);
    }

    float pel[4], per[4];
    const float alv = al[m];
    const float arv = ar[m];
#pragma unroll
    for (int reg = 0; reg < 4; ++reg) {
        int row = rb + q * 4 + reg;
        float a = acc0[reg];
        if (row < nrows) {
            feat2b[(size_t)row * 16 + m] = f2bf(a);
            res2[(size_t)row * 16 + m]   = acc1[reg];
        }
        pel[reg] = a * alv;
        per[reg] = a * arv;
    }
#pragma unroll
    for (int sh = 8; sh > 0; sh >>= 1) {
#pragma unroll
        for (int reg = 0; reg < 4; ++reg) {
            pel[reg] += __shfl_down(pel[reg], sh);
            per[reg] += __shfl_down(per[reg], sh);
        }
    }
    if (m == 0) {
#pragma unroll
        for (int reg = 0; reg < 4; ++reg) {
            int row = rb + q * 4 + reg;
            if (row < nrows) { el[row] = pel[reg]; er[row] = per[reg]; }
        }
    }
}

// ---------------------------------------------------------------------------
// Pull aggregation, H=4, D=32, bf16 gathers, wave per node, bf16 in/out.
// EXACT round-10 structure (78.5 us) — readfirstlane, half-wave split, and
// nt hints all regressed this kernel; it is memory-latency bound.
// ---------------------------------------------------------------------------
__global__ __launch_bounds__(256) void gat_agg128(const int* __restrict__ rowptr,
                                                  const int* __restrict__ deg,
                                                  const int* __restrict__ sorted_src,
                                                  const float* __restrict__ el,
                                                  const float* __restrict__ er,
                                                  const unsigned short* __restrict__ featb,
                                                  const unsigned short* __restrict__ resb,
                                                  unsigned short* __restrict__ outb) {
    __shared__ int   sS[4][64];
    __shared__ float sW[4][64][4];

    const int wv   = threadIdx.x >> 6;
    const int lane = threadIdx.x & 63;
    const int nd   = blockIdx.x * 4 + wv;

    const int dg = deg[nd];
    const int r0 = rowptr[nd];
    const int h  = lane >> 4;
    const float4 er4 = *(const float4*)(er + nd * 4);

    float den = 0.f;
    float ax = 0.f, ay = 0.f;

    for (int base = 0; base < dg; base += 64) {
        int m = dg - base; if (m > 64) m = 64;
        if (lane < m) {
            int s = sorted_src[r0 + base + lane];
            sS[wv][lane] = s;
            float4 e4 = *(const float4*)(el + s * 4);
            float4 w;
            float v;
            v = e4.x + er4.x; v = v > 0.f ? v : NEG_SLOPE * v; w.x = __expf(v);
            v = e4.y + er4.y; v = v > 0.f ? v : NEG_SLOPE * v; w.y = __expf(v);
            v = e4.z + er4.z; v = v > 0.f ? v : NEG_SLOPE * v; w.z = __expf(v);
            v = e4.w + er4.w; v = v > 0.f ? v : NEG_SLOPE * v; w.w = __expf(v);
            *(float4*)(&sW[wv][lane][0]) = w;
        }
        // wave-synchronous: same wave wrote LDS
        for (int i = 0; i < m; ++i) {
            int s   = sS[wv][i];
            float w = sW[wv][i][h];
            den += w;
            ushort2 u = *((const ushort2*)(featb + (size_t)s * 128) + lane);
            ax += w * bf2f(u.x);
            ay += w * bf2f(u.y);
        }
    }

    float scale = den > 0.f ? 1.f / den : 0.f;
    float ox = ax * scale, oy = ay * scale;
    size_t o0 = (size_t)nd * 128 + lane * 2;
    if (resb) {
        ushort2 rv = *(const ushort2*)(resb + o0);
        ox += bf2f(rv.x);
        oy += bf2f(rv.y);
    }
    ox = fmaxf(ox, 0.f);
    oy = fmaxf(oy, 0.f);
    ushort2 ou;
    ou.x = f2bf(ox);
    ou.y = f2bf(oy);
    *(ushort2*)(outb + o0) = ou;
}

// ---------------------------------------------------------------------------
// Pull aggregation, H=1, C=16: wave per node, LDS staging, 8 edge-groups of
// 8 lanes; lane owns a feature pair. Final output f32 (+res2).
// ---------------------------------------------------------------------------
__global__ __launch_bounds__(256) void gat_agg16(const int* __restrict__ rowptr,
                                                 const int* __restrict__ deg,
                                                 const int* __restrict__ sorted_src,
                                                 const float* __restrict__ el,
                                                 const float* __restrict__ er,
                                                 const unsigned short* __restrict__ feat2b,
                                                 const float* __restrict__ res,
                                                 float* __restrict__ out) {
    __shared__ int   sS[4][64];
    __shared__ float sW[4][64];

    const int wv   = threadIdx.x >> 6;
    const int lane = threadIdx.x & 63;
    const int nd   = blockIdx.x * 4 + wv;
    const int g    = lane >> 3;
    const int f2   = (lane & 7) * 2;

    const int dg = deg[nd];
    const int r0 = rowptr[nd];
    const float erd = er[nd];

    float ax = 0.f, ay = 0.f, den = 0.f;

    for (int base = 0; base < dg; base += 64) {
        int m = dg - base; if (m > 64) m = 64;
        if (lane < m) {
            int s = sorted_src[r0 + base + lane];
            sS[wv][lane] = s;
            float v = el[s] + erd;
            v = v > 0.f ? v : NEG_SLOPE * v;
            sW[wv][lane] = __expf(v);
        }
        for (int i = g; i < m; i += 8) {
            int s   = sS[wv][i];
            float w = sW[wv][i];
            den += w;
            ushort2 u = *(const ushort2*)(feat2b + (size_t)s * 16 + f2);
            ax += w * bf2f(u.x);
            ay += w * bf2f(u.y);
        }
    }

    ax += __shfl_down(ax, 32); ay += __shfl_down(ay, 32); den += __shfl_down(den, 32);
    ax += __shfl_down(ax, 16); ay += __shfl_down(ay, 16); den += __shfl_down(den, 16);
    ax += __shfl_down(ax, 8);  ay += __shfl_down(ay, 8);  den += __shfl_down(den, 8);

    if (lane < 8) {
        float scale = den > 0.f ? 1.f / den : 0.f;
        size_t o0 = (size_t)nd * 16 + f2;
        float2 o;
        o.x = ax * scale + res[o0];
        o.y = ay * scale + res[o0 + 1];
        *(float2*)(out + o0) = o;
    }
}

// ---------------------------------------------------------------------------
extern "C" void kernel_launch(void* const* d_in, const int* in_sizes, int n_in,
                              void* d_out, int out_size, void* d_ws, size_t ws_size,
                              hipStream_t stream) {
    const float* inputs = (const float*)d_in[0];
    const int*   src    = (const int*)d_in[1];
    const int*   dst    = (const int*)d_in[2];
    const float* W0     = (const float*)d_in[3];
    const float* al0    = (const float*)d_in[4];
    const float* ar0    = (const float*)d_in[5];
    const float* W1     = (const float*)d_in[6];
    const float* al1    = (const float*)d_in[7];
    const float* ar1    = (const float*)d_in[8];
    const float* W2     = (const float*)d_in[9];
    const float* al2    = (const float*)d_in[10];
    const float* ar2    = (const float*)d_in[11];
    const float* resW2  = (const float*)d_in[12];
    float* out = (float*)d_out;

    const size_t NF = (size_t)N_NODES * 128;
    float* ws   = (float*)d_ws;
    float* el   = ws;                                  // N*4
    float* er   = el + (size_t)N_NODES * 4;            // N*4
    float* res2 = er + (size_t)N_NODES * 4;            // N*16
    unsigned short* hbufb  = (unsigned short*)(res2 + (size_t)N_NODES * 16);  // N*128 bf16
    unsigned short* featb  = hbufb + NF;               // N*128 bf16
    unsigned short* feat2b = featb + NF;               // N*16 bf16
    unsigned short* W0p    = feat2b + (size_t)N_NODES * 16;  // 16384
    unsigned short* W1p    = W0p + 16384;                    // 16384
    unsigned short* W2p    = W1p + 16384;                    // 8192
    int* iws = (int*)(W2p + 8192);
    unsigned int* pe = (unsigned int*)iws;             // NBUCK*BCAP padded
    int* sorted_src  = iws + NBUCK * BCAP;             // NBUCK*BCAP padded
    int* deg         = sorted_src + NBUCK * BCAP;      // N
    int* rowptr      = deg + N_NODES;                  // N
    int* bcursor     = rowptr + N_NODES;               // 512

    dim3 blk(256);
    int aggGrid = N_NODES / 4;                         // 25000

    // ---- K1: cursor init + weight pack ----
    init_pack<<<162, blk, 0, stream>>>(bcursor, W0, W1, W2, resW2, W0p, W1p, W2p);
    // ---- K2: partition + layer-0 GEMM ----
    part_gemm0<<<PGRID + GEMMGRID, blk, 0, stream>>>(src, dst, bcursor, pe, N_EDGES,
                                                     inputs, W0p, al0, ar0, featb,
                                                     el, er, N_NODES);
    // ---- K3: finalize CSR ----
    bucket_finalize<<<PGRID, blk, 0, stream>>>(pe, bcursor, rowptr, deg, sorted_src);

    // ---- layer 0 aggregation ----
    gat_agg128<<<aggGrid, blk, 0, stream>>>(rowptr, deg, sorted_src, el, er, featb,
                                            nullptr, hbufb);

    // ---- layer 1 ----
    gemm128_mfma_bf16<<<GEMMGRID, blk, 0, stream>>>(hbufb, W1p, al1, ar1, featb,
                                                    el, er, N_NODES);
    gat_agg128<<<aggGrid, blk, 0, stream>>>(rowptr, deg, sorted_src, el, er, featb,
                                            hbufb, hbufb);

    // ---- layer 2 ----
    gemm16_mfma<<<GEMMGRID, blk, 0, stream>>>(hbufb, W2p, al2, ar2, feat2b, res2,
                                              el, er, N_NODES);
    gat_agg16<<<aggGrid, blk, 0, stream>>>(rowptr, deg, sorted_src, el, er, feat2b,
                                           res2, out);
}

// Round 14
// 385.598 us; speedup vs baseline: 1.1024x; 1.0038x over previous
//
#include <hip/hip_runtime.h>

#define N_NODES 100000
#define N_EDGES 1600000
#define IN_F    128
#define NEG_SLOPE 0.2f
#define NBUCK   512                 // bucket = dst>>8; 391 active
#define BCAP    5120                // padded bucket capacity (mean 4096, +16 sigma)
#define PCHUNK  4096                // edges per partition block
#define PGRID   391                 // ceil(N_EDGES / PCHUNK)
#define GEMMGRID 1563               // ceil(N_NODES / 64)

typedef __attribute__((ext_vector_type(8))) short bf16x8;
typedef __attribute__((ext_vector_type(4))) float f32x4;

__device__ __forceinline__ float bf2f(unsigned short u) {
    return __uint_as_float(((unsigned int)u) << 16);
}

// f32 -> bf16 round-to-nearest-even
__device__ __forceinline__ unsigned short f2bf(float f) {
    unsigned int u = __float_as_uint(f);
    u += 0x7FFFu + ((u >> 16) & 1u);
    return (unsigned short)(u >> 16);
}

// ---------------------------------------------------------------------------
// K1: cursor init (blocks 0..1) + weight pack (blocks 2..161).
// Pack layout: Wp[((nt*4+kt)*64+lane)*8+j] = W[kt*32+(lane>>4)*8+j][nt*16+(lane&15)]
// ---------------------------------------------------------------------------
__global__ __launch_bounds__(256) void init_pack(int* __restrict__ bcursor,
                                                 const float* __restrict__ W0,
                                                 const float* __restrict__ W1,
                                                 const float* __restrict__ W2,
                                                 const float* __restrict__ rW2,
                                                 unsigned short* __restrict__ W0p,
                                                 unsigned short* __restrict__ W1p,
                                                 unsigned short* __restrict__ W2p) {
    const int t = threadIdx.x;
    if (blockIdx.x < 2) {
        int i = blockIdx.x * 256 + t;
        if (i < NBUCK) bcursor[i] = i * BCAP;
        return;
    }
    int gid = (blockIdx.x - 2) * 256 + t;            // < 40960
    const float* W;
    unsigned short* Wp;
    int idx, ncols;
    if (gid < 16384)      { W = W0; Wp = W0p; idx = gid;          ncols = 128; }
    else if (gid < 32768) { W = W1; Wp = W1p; idx = gid - 16384;  ncols = 128; }
    else                  { W = W2; Wp = W2p; idx = gid - 32768;  ncols = 32;  }
    int j  = idx & 7;
    int l  = (idx >> 3) & 63;
    int kt = (idx >> 9) & 3;
    int nt = idx >> 11;
    int k  = kt * 32 + (l >> 4) * 8 + j;
    int n  = nt * 16 + (l & 15);
    float v;
    if (ncols == 128) v = W[k * 128 + n];
    else              v = (n < 16) ? W[k * 16 + n] : rW2[k * 16 + (n - 16)];
    Wp[idx] = f2bf(v);
}

// ---------------------------------------------------------------------------
// K2: edge partition into padded buckets (blocks [0,PGRID)) + layer-0 MFMA
// GEMM (blocks [PGRID, PGRID+GEMMGRID)).
// ---------------------------------------------------------------------------
__global__ __launch_bounds__(256) void part_gemm0(const int* __restrict__ src,
                                                  const int* __restrict__ dst,
                                                  int* __restrict__ bcursor,
                                                  unsigned int* __restrict__ pe, int nE,
                                                  const float* __restrict__ A,
                                                  const unsigned short* __restrict__ Wp,
                                                  const float* __restrict__ al,
                                                  const float* __restrict__ ar,
                                                  unsigned short* __restrict__ featb,
                                                  float* __restrict__ el,
                                                  float* __restrict__ er,
                                                  int nrows) {
    __shared__ int hist[NBUCK];
    __shared__ int lstart[NBUCK];
    __shared__ int gbase[NBUCK];
    __shared__ int curB[NBUCK];
    __shared__ int s[NBUCK];
    __shared__ unsigned int reorder[PCHUNK];

    const int t = threadIdx.x;

    if (blockIdx.x < PGRID) {
        const int start = blockIdx.x * PCHUNK;

        hist[t] = 0; hist[t + 256] = 0;
        __syncthreads();
#pragma unroll
        for (int j = 0; j < PCHUNK / 256; ++j) {
            int e = start + j * 256 + t;
            if (e < nE) atomicAdd(&hist[dst[e] >> 8], 1);
        }
        __syncthreads();
        const int c0 = hist[t];
        const int c1 = hist[t + 256];
        s[t] = c0; s[t + 256] = c1;
        __syncthreads();
        // 512-wide inclusive scan with 256 threads
#pragma unroll
        for (int off = 1; off <= 256; off <<= 1) {
            int x0 = (t >= off) ? s[t - off] : 0;
            int x1 = s[t + 256 - off];
            __syncthreads();
            s[t] += x0; s[t + 256] += x1;
            __syncthreads();
        }
        lstart[t]       = s[t] - c0;
        lstart[t + 256] = s[t + 256] - c1;
        curB[t]         = s[t] - c0;
        curB[t + 256]   = s[t + 256] - c1;
        gbase[t]        = c0 ? atomicAdd(&bcursor[t],       c0) : 0;
        gbase[t + 256]  = c1 ? atomicAdd(&bcursor[t + 256], c1) : 0;
        __syncthreads();

#pragma unroll
        for (int j = 0; j < PCHUNK / 256; ++j) {
            int e = start + j * 256 + t;
            if (e < nE) {
                int d  = dst[e];
                int sv = src[e];
                int b  = d >> 8;
                int pos = atomicAdd(&curB[b], 1);
                reorder[pos] = ((unsigned)sv << 8) | ((unsigned)d & 255u);
            }
        }
        __syncthreads();

        // flush: one thread per bucket writes its contiguous run
        for (int b = t; b < NBUCK; b += 256) {
            int st = lstart[b];
            int en = curB[b];
            int gb = gbase[b];
            for (int k = st; k < en; ++k)
                pe[gb + (k - st)] = reorder[k];
        }
    } else {
        // ---------------- layer-0 GEMM ----------------
        const int bid  = blockIdx.x - PGRID;
        const int wv   = t >> 6;
        const int lane = t & 63;
        const int q    = lane >> 4;
        const int m    = lane & 15;
        const int rb   = bid * 64 + wv * 16;
        const int arow = rb + m;
        const bool rok = arow < nrows;
        const float* Ar = A + (size_t)arow * IN_F;

        f32x4 acc[8];
#pragma unroll
        for (int nt = 0; nt < 8; ++nt) acc[nt] = (f32x4){0.f, 0.f, 0.f, 0.f};

#pragma unroll
        for (int kt = 0; kt < 4; ++kt) {
            bf16x8 afr = (bf16x8){0, 0, 0, 0, 0, 0, 0, 0};
            if (rok) {
                float4 v0 = *(const float4*)(Ar + kt * 32 + q * 8);
                float4 v1 = *(const float4*)(Ar + kt * 32 + q * 8 + 4);
                afr[0] = (short)f2bf(v0.x); afr[1] = (short)f2bf(v0.y);
                afr[2] = (short)f2bf(v0.z); afr[3] = (short)f2bf(v0.w);
                afr[4] = (short)f2bf(v1.x); afr[5] = (short)f2bf(v1.y);
                afr[6] = (short)f2bf(v1.z); afr[7] = (short)f2bf(v1.w);
            }
#pragma unroll
            for (int nt = 0; nt < 8; ++nt) {
                bf16x8 bfr = *(const bf16x8*)(Wp + ((size_t)(nt * 4 + kt) * 64 + lane) * 8);
                acc[nt] = __builtin_amdgcn_mfma_f32_16x16x32_bf16(afr, bfr, acc[nt], 0, 0, 0);
            }
        }

        float pel[16], per[16];
#pragma unroll
        for (int i = 0; i < 16; ++i) { pel[i] = 0.f; per[i] = 0.f; }

#pragma unroll
        for (int nt = 0; nt < 8; ++nt) {
            const int col = nt * 16 + m;
            const float alv = al[col];
            const float arv = ar[col];
            const int h = nt >> 1;
#pragma unroll
            for (int reg = 0; reg < 4; ++reg) {
                int row = rb + q * 4 + reg;
                float a = acc[nt][reg];
                if (row < nrows) featb[(size_t)row * 128 + col] = f2bf(a);
                pel[reg * 4 + h] += a * alv;
                per[reg * 4 + h] += a * arv;
            }
        }
#pragma unroll
        for (int sh = 8; sh > 0; sh >>= 1) {
#pragma unroll
            for (int i = 0; i < 16; ++i) {
                pel[i] += __shfl_down(pel[i], sh);
                per[i] += __shfl_down(per[i], sh);
            }
        }
        if (m == 0) {
#pragma unroll
            for (int reg = 0; reg < 4; ++reg) {
                int row = rb + q * 4 + reg;
                if (row < nrows) {
#pragma unroll
                    for (int h = 0; h < 4; ++h) {
                        el[row * 4 + h] = pel[reg * 4 + h];
                        er[row * 4 + h] = per[reg * 4 + h];
                    }
                }
            }
        }
    }
}

// ---------------------------------------------------------------------------
// K3: per-bucket finalize — degree histogram + local scan -> rowptr/deg,
// within-bucket sort -> sorted_src (padded space, base = b*BCAP).
// ---------------------------------------------------------------------------
__global__ __launch_bounds__(256) void bucket_finalize(const unsigned int* __restrict__ pe,
                                                       const int* __restrict__ bcursor,
                                                       int* __restrict__ rowptr,
                                                       int* __restrict__ deg,
                                                       int* __restrict__ sorted_src) {
    __shared__ int deg_l[256];
    __shared__ int s[256];
    __shared__ int cur[256];

    const int b  = blockIdx.x;
    const int t  = threadIdx.x;
    const int base = b * BCAP;
    const int cnt  = bcursor[b] - base;
    const int n    = b * 256 + t;

    deg_l[t] = 0;
    __syncthreads();
    for (int i = t; i < cnt; i += 256)
        atomicAdd(&deg_l[pe[base + i] & 255u], 1);
    __syncthreads();

    const int dv = deg_l[t];
    s[t] = dv;
    __syncthreads();
#pragma unroll
    for (int off = 1; off < 256; off <<= 1) {
        int x = (t >= off) ? s[t - off] : 0;
        __syncthreads();
        s[t] += x;
        __syncthreads();
    }
    const int off_l = s[t] - dv;
    if (n < N_NODES) {
        rowptr[n] = base + off_l;
        deg[n]    = dv;
    }
    cur[t] = off_l;
    __syncthreads();

    for (int i = t; i < cnt; i += 256) {
        unsigned int ed = pe[base + i];
        int pos = atomicAdd(&cur[ed & 255u], 1);
        sorted_src[base + pos] = (int)(ed >> 8);
    }
}

// ---------------------------------------------------------------------------
// MFMA GEMM, bf16 A (layer 1): featb = Ab @ Wp, el/er fused. Barrier-free.
// ---------------------------------------------------------------------------
__global__ __launch_bounds__(256) void gemm128_mfma_bf16(const unsigned short* __restrict__ Ab,
                                                         const unsigned short* __restrict__ Wp,
                                                         const float* __restrict__ al,
                                                         const float* __restrict__ ar,
                                                         unsigned short* __restrict__ featb,
                                                         float* __restrict__ el,
                                                         float* __restrict__ er,
                                                         int nrows) {
    const int t    = threadIdx.x;
    const int wv   = t >> 6;
    const int lane = t & 63;
    const int q    = lane >> 4;
    const int m    = lane & 15;
    const int rb   = blockIdx.x * 64 + wv * 16;
    const int arow = rb + m;
    const bool rok = arow < nrows;
    const unsigned short* Ar = Ab + (size_t)arow * IN_F;

    f32x4 acc[8];
#pragma unroll
    for (int nt = 0; nt < 8; ++nt) acc[nt] = (f32x4){0.f, 0.f, 0.f, 0.f};

#pragma unroll
    for (int kt = 0; kt < 4; ++kt) {
        bf16x8 afr = (bf16x8){0, 0, 0, 0, 0, 0, 0, 0};
        if (rok) afr = *(const bf16x8*)(Ar + kt * 32 + q * 8);
#pragma unroll
        for (int nt = 0; nt < 8; ++nt) {
            bf16x8 bfr = *(const bf16x8*)(Wp + ((size_t)(nt * 4 + kt) * 64 + lane) * 8);
            acc[nt] = __builtin_amdgcn_mfma_f32_16x16x32_bf16(afr, bfr, acc[nt], 0, 0, 0);
        }
    }

    float pel[16], per[16];
#pragma unroll
    for (int i = 0; i < 16; ++i) { pel[i] = 0.f; per[i] = 0.f; }

#pragma unroll
    for (int nt = 0; nt < 8; ++nt) {
        const int col = nt * 16 + m;
        const float alv = al[col];
        const float arv = ar[col];
        const int h = nt >> 1;
#pragma unroll
        for (int reg = 0; reg < 4; ++reg) {
            int row = rb + q * 4 + reg;
            float a = acc[nt][reg];
            if (row < nrows) featb[(size_t)row * 128 + col] = f2bf(a);
            pel[reg * 4 + h] += a * alv;
            per[reg * 4 + h] += a * arv;
        }
    }
#pragma unroll
    for (int sh = 8; sh > 0; sh >>= 1) {
#pragma unroll
        for (int i = 0; i < 16; ++i) {
            pel[i] += __shfl_down(pel[i], sh);
            per[i] += __shfl_down(per[i], sh);
        }
    }
    if (m == 0) {
#pragma unroll
        for (int reg = 0; reg < 4; ++reg) {
            int row = rb + q * 4 + reg;
            if (row < nrows) {
#pragma unroll
                for (int h = 0; h < 4; ++h) {
                    el[row * 4 + h] = pel[reg * 4 + h];
                    er[row * 4 + h] = per[reg * 4 + h];
                }
            }
        }
    }
}

// ---------------------------------------------------------------------------
// MFMA dual GEMM layer 2 (bf16 A): [feat2b(bf16) | res2(f32)] = A @ [W2|resW2].
// ---------------------------------------------------------------------------
__global__ __launch_bounds__(256) void gemm16_mfma(const unsigned short* __restrict__ Ab,
                                                   const unsigned short* __restrict__ Wp,
                                                   const float* __restrict__ al,
                                                   const float* __restrict__ ar,
                                                   unsigned short* __restrict__ feat2b,
                                                   float* __restrict__ res2,
                                                   float* __restrict__ el,
                                                   float* __restrict__ er,
                                                   int nrows) {
    const int t    = threadIdx.x;
    const int wv   = t >> 6;
    const int lane = t & 63;
    const int q    = lane >> 4;
    const int m    = lane & 15;
    const int rb   = blockIdx.x * 64 + wv * 16;
    const int arow = rb + m;
    const bool rok = arow < nrows;
    const unsigned short* Ar = Ab + (size_t)arow * IN_F;

    f32x4 acc0 = (f32x4){0.f, 0.f, 0.f, 0.f};
    f32x4 acc1 = (f32x4){0.f, 0.f, 0.f, 0.f};

#pragma unroll
    for (int kt = 0; kt < 4; ++kt) {
        bf16x8 afr = (bf16x8){0, 0, 0, 0, 0, 0, 0, 0};
        if (rok) afr = *(const bf16x8*)(Ar + kt * 32 + q * 8);
        bf16x8 b0 = *(const bf16x8*)(Wp + ((size_t)(0 * 4 + kt) * 64 + lane) * 8);
        bf16x8 b1 = *(const bf16x8*)(Wp + ((size_t)(1 * 4 + kt) * 64 + lane) * 8);
        acc0 = __builtin_amdgcn_mfma_f32_16x16x32_bf16(afr, b0, acc0, 0, 0, 0);
        acc1 = __builtin_amdgcn_mfma_f32_16x16x32_bf16(afr, b1, acc1, 0, 0, 0);
    }

    float pel[4], per[4];
    const float alv = al[m];
    const float arv = ar[m];
#pragma unroll
    for (int reg = 0; reg < 4; ++reg) {
        int row = rb + q * 4 + reg;
        float a = acc0[reg];
        if (row < nrows) {
            feat2b[(size_t)row * 16 + m] = f2bf(a);
            res2[(size_t)row * 16 + m]   = acc1[reg];
        }
        pel[reg] = a * alv;
        per[reg] = a * arv;
    }
#pragma unroll
    for (int sh = 8; sh > 0; sh >>= 1) {
#pragma unroll
        for (int reg = 0; reg < 4; ++reg) {
            pel[reg] += __shfl_down(pel[reg], sh);
            per[reg] += __shfl_down(per[reg], sh);
        }
    }
    if (m == 0) {
#pragma unroll
        for (int reg = 0; reg < 4; ++reg) {
            int row = rb + q * 4 + reg;
            if (row < nrows) { el[row] = pel[reg]; er[row] = per[reg]; }
        }
    }
}

// ---------------------------------------------------------------------------
// Pull aggregation, H=4, D=32, bf16 gathers, wave per node, bf16 in/out.
// x4-unrolled gather loop: four independent full-row loads in flight per wave
// (plain vector addressing, 256B per load instruction — the two prior
// regressions came from changing the access pattern / address path, not
// from MLP itself).
// ---------------------------------------------------------------------------
__global__ __launch_bounds__(256) void gat_agg128(const int* __restrict__ rowptr,
                                                  const int* __restrict__ deg,
                                                  const int* __restrict__ sorted_src,
                                                  const float* __restrict__ el,
                                                  const float* __restrict__ er,
                                                  const unsigned short* __restrict__ featb,
                                                  const unsigned short* __restrict__ resb,
                                                  unsigned short* __restrict__ outb) {
    __shared__ int   sS[4][64];
    __shared__ float sW[4][64][4];

    const int wv   = threadIdx.x >> 6;
    const int lane = threadIdx.x & 63;
    const int nd   = blockIdx.x * 4 + wv;

    const int dg = deg[nd];
    const int r0 = rowptr[nd];
    const int h  = lane >> 4;
    const float4 er4 = *(const float4*)(er + nd * 4);

    float den = 0.f;
    float ax = 0.f, ay = 0.f;

    for (int base = 0; base < dg; base += 64) {
        int m = dg - base; if (m > 64) m = 64;
        if (lane < m) {
            int s = sorted_src[r0 + base + lane];
            sS[wv][lane] = s;
            float4 e4 = *(const float4*)(el + s * 4);
            float4 w;
            float v;
            v = e4.x + er4.x; v = v > 0.f ? v : NEG_SLOPE * v; w.x = __expf(v);
            v = e4.y + er4.y; v = v > 0.f ? v : NEG_SLOPE * v; w.y = __expf(v);
            v = e4.z + er4.z; v = v > 0.f ? v : NEG_SLOPE * v; w.z = __expf(v);
            v = e4.w + er4.w; v = v > 0.f ? v : NEG_SLOPE * v; w.w = __expf(v);
            *(float4*)(&sW[wv][lane][0]) = w;
        }
        // wave-synchronous: same wave wrote LDS
        int i = 0;
        for (; i + 3 < m; i += 4) {
            int s0 = sS[wv][i];
            int s1 = sS[wv][i + 1];
            int s2 = sS[wv][i + 2];
            int s3 = sS[wv][i + 3];
            float w0 = sW[wv][i][h];
            float w1 = sW[wv][i + 1][h];
            float w2 = sW[wv][i + 2][h];
            float w3 = sW[wv][i + 3][h];
            ushort2 u0 = *((const ushort2*)(featb + (size_t)s0 * 128) + lane);
            ushort2 u1 = *((const ushort2*)(featb + (size_t)s1 * 128) + lane);
            ushort2 u2 = *((const ushort2*)(featb + (size_t)s2 * 128) + lane);
            ushort2 u3 = *((const ushort2*)(featb + (size_t)s3 * 128) + lane);
            den += w0 + w1 + w2 + w3;
            ax += w0 * bf2f(u0.x);
            ay += w0 * bf2f(u0.y);
            ax += w1 * bf2f(u1.x);
            ay += w1 * bf2f(u1.y);
            ax += w2 * bf2f(u2.x);
            ay += w2 * bf2f(u2.y);
            ax += w3 * bf2f(u3.x);
            ay += w3 * bf2f(u3.y);
        }
        for (; i < m; ++i) {
            int s   = sS[wv][i];
            float w = sW[wv][i][h];
            den += w;
            ushort2 u = *((const ushort2*)(featb + (size_t)s * 128) + lane);
            ax += w * bf2f(u.x);
            ay += w * bf2f(u.y);
        }
    }

    float scale = den > 0.f ? 1.f / den : 0.f;
    float ox = ax * scale, oy = ay * scale;
    size_t o0 = (size_t)nd * 128 + lane * 2;
    if (resb) {
        ushort2 rv = *(const ushort2*)(resb + o0);
        ox += bf2f(rv.x);
        oy += bf2f(rv.y);
    }
    ox = fmaxf(ox, 0.f);
    oy = fmaxf(oy, 0.f);
    ushort2 ou;
    ou.x = f2bf(ox);
    ou.y = f2bf(oy);
    *(ushort2*)(outb + o0) = ou;
}

// ---------------------------------------------------------------------------
// Pull aggregation, H=1, C=16: wave per node, LDS staging, 8 edge-groups of
// 8 lanes; lane owns a feature pair. Final output f32 (+res2).
// ---------------------------------------------------------------------------
__global__ __launch_bounds__(256) void gat_agg16(const int* __restrict__ rowptr,
                                                 const int* __restrict__ deg,
                                                 const int* __restrict__ sorted_src,
                                                 const float* __restrict__ el,
                                                 const float* __restrict__ er,
                                                 const unsigned short* __restrict__ feat2b,
                                                 const float* __restrict__ res,
                                                 float* __restrict__ out) {
    __shared__ int   sS[4][64];
    __shared__ float sW[4][64];

    const int wv   = threadIdx.x >> 6;
    const int lane = threadIdx.x & 63;
    const int nd   = blockIdx.x * 4 + (threadIdx.x >> 6);
    const int g    = lane >> 3;
    const int f2   = (lane & 7) * 2;

    const int dg = deg[nd];
    const int r0 = rowptr[nd];
    const float erd = er[nd];

    float ax = 0.f, ay = 0.f, den = 0.f;

    for (int base = 0; base < dg; base += 64) {
        int m = dg - base; if (m > 64) m = 64;
        if (lane < m) {
            int s = sorted_src[r0 + base + lane];
            sS[wv][lane] = s;
            float v = el[s] + erd;
            v = v > 0.f ? v : NEG_SLOPE * v;
            sW[wv][lane] = __expf(v);
        }
        for (int i = g; i < m; i += 8) {
            int s   = sS[wv][i];
            float w = sW[wv][i];
            den += w;
            ushort2 u = *(const ushort2*)(feat2b + (size_t)s * 16 + f2);
            ax += w * bf2f(u.x);
            ay += w * bf2f(u.y);
        }
    }

    ax += __shfl_down(ax, 32); ay += __shfl_down(ay, 32); den += __shfl_down(den, 32);
    ax += __shfl_down(ax, 16); ay += __shfl_down(ay, 16); den += __shfl_down(den, 16);
    ax += __shfl_down(ax, 8);  ay += __shfl_down(ay, 8);  den += __shfl_down(den, 8);

    if (lane < 8) {
        float scale = den > 0.f ? 1.f / den : 0.f;
        size_t o0 = (size_t)nd * 16 + f2;
        float2 o;
        o.x = ax * scale + res[o0];
        o.y = ay * scale + res[o0 + 1];
        *(float2*)(out + o0) = o;
    }
}

// ---------------------------------------------------------------------------
extern "C" void kernel_launch(void* const* d_in, const int* in_sizes, int n_in,
                              void* d_out, int out_size, void* d_ws, size_t ws_size,
                              hipStream_t stream) {
    const float* inputs = (const float*)d_in[0];
    const int*   src    = (const int*)d_in[1];
    const int*   dst    = (const int*)d_in[2];
    const float* W0     = (const float*)d_in[3];
    const float* al0    = (const float*)d_in[4];
    const float* ar0    = (const float*)d_in[5];
    const float* W1     = (const float*)d_in[6];
    const float* al1    = (const float*)d_in[7];
    const float* ar1    = (const float*)d_in[8];
    const float* W2     = (const float*)d_in[9];
    const float* al2    = (const float*)d_in[10];
    const float* ar2    = (const float*)d_in[11];
    const float* resW2  = (const float*)d_in[12];
    float* out = (float*)d_out;

    const size_t NF = (size_t)N_NODES * 128;
    float* ws   = (float*)d_ws;
    float* el   = ws;                                  // N*4
    float* er   = el + (size_t)N_NODES * 4;            // N*4
    float* res2 = er + (size_t)N_NODES * 4;            // N*16
    unsigned short* hbufb  = (unsigned short*)(res2 + (size_t)N_NODES * 16);  // N*128 bf16
    unsigned short* featb  = hbufb + NF;               // N*128 bf16
    unsigned short* feat2b = featb + NF;               // N*16 bf16
    unsigned short* W0p    = feat2b + (size_t)N_NODES * 16;  // 16384
    unsigned short* W1p    = W0p + 16384;                    // 16384
    unsigned short* W2p    = W1p + 16384;                    // 8192
    int* iws = (int*)(W2p + 8192);
    unsigned int* pe = (unsigned int*)iws;             // NBUCK*BCAP padded
    int* sorted_src  = iws + NBUCK * BCAP;             // NBUCK*BCAP padded
    int* deg         = sorted_src + NBUCK * BCAP;      // N
    int* rowptr      = deg + N_NODES;                  // N
    int* bcursor     = rowptr + N_NODES;               // 512

    dim3 blk(256);
    int aggGrid = N_NODES / 4;                         // 25000

    // ---- K1: cursor init + weight pack ----
    init_pack<<<162, blk, 0, stream>>>(bcursor, W0, W1, W2, resW2, W0p, W1p, W2p);
    // ---- K2: partition + layer-0 GEMM ----
    part_gemm0<<<PGRID + GEMMGRID, blk, 0, stream>>>(src, dst, bcursor, pe, N_EDGES,
                                                     inputs, W0p, al0, ar0, featb,
                                                     el, er, N_NODES);
    // ---- K3: finalize CSR ----
    bucket_finalize<<<PGRID, blk, 0, stream>>>(pe, bcursor, rowptr, deg, sorted_src);

    // ---- layer 0 aggregation ----
    gat_agg128<<<aggGrid, blk, 0, stream>>>(rowptr, deg, sorted_src, el, er, featb,
                                            nullptr, hbufb);

    // ---- layer 1 ----
    gemm128_mfma_bf16<<<GEMMGRID, blk, 0, stream>>>(hbufb, W1p, al1, ar1, featb,
                                                    el, er, N_NODES);
    gat_agg128<<<aggGrid, blk, 0, stream>>>(rowptr, deg, sorted_src, el, er, featb,
                                            hbufb, hbufb);

    // ---- layer 2 ----
    gemm16_mfma<<<GEMMGRID, blk, 0, stream>>>(hbufb, W2p, al2, ar2, feat2b, res2,
                                              el, er, N_NODES);
    gat_agg16<<<aggGrid, blk, 0, stream>>>(rowptr, deg, sorted_src, el, er, feat2b,
                                           res2, out);
}